// Round 11
// baseline (451.995 us; speedup 1.0000x reference)
//
#include <hip/hip_runtime.h>
#include <stdint.h>

typedef unsigned int u32;
typedef unsigned short u16;
typedef unsigned long long u64;
typedef __attribute__((ext_vector_type(8))) short short8;
typedef __attribute__((ext_vector_type(4))) float f32x4;

#define N8K 8192

__device__ __forceinline__ float b2f(u16 u) { return __uint_as_float(((u32)u) << 16); }
__device__ __forceinline__ u16 f2b(float f) {
  u32 i = __float_as_uint(f);
  i += 0x7FFFu + ((i >> 16) & 1u);
  return (u16)(i >> 16);
}
// fp16 (RNE) helpers for split-K partials
__device__ __forceinline__ u16 f2h(float f) {
  union { _Float16 h; u16 u; } x; x.h = (_Float16)f; return x.u;
}
__device__ __forceinline__ u32 pkh(float a, float b) {
  return (u32)f2h(a) | ((u32)f2h(b) << 16);
}
union H8 { uint4 u; _Float16 h[8]; };
union H2 { u32 u; _Float16 h[2]; };
// pack two 0/1 ints into two bf16 halves
__device__ __forceinline__ u32 pk01(int x, int y) { return (u32)__mul24(x | (y << 16), 0x3F80); }
__device__ __forceinline__ u32 pkf(float a, float b) { return (u32)f2b(a) | ((u32)f2b(b) << 16); }

// block-uniform dtype vote: 1 = tensors are bf16, 0 = fp32
__device__ __forceinline__ int dvote(const u16* f16) {
  u16 u = f16[threadIdx.x * 2];
  int e = (u >> 7) & 0xFF;
  return __syncthreads_count((e >= 0x60 && e <= 0x9F) ? 1 : 0) >= 128;
}

// async global->LDS, 16B/lane; lds dest wave-uniform base (+lane*16)
__device__ __forceinline__ void gl_lds16(const void* g, void* l) {
  __builtin_amdgcn_global_load_lds(
      (const __attribute__((address_space(1))) u32*)g,
      (__attribute__((address_space(3))) u32*)l, 16, 0, 0);
}

// 16 bits (0/1 adjacency) -> 8 u32 bf16-pairs (1.0f bf16 = 0x3F80)
__device__ __forceinline__ void unpack16(u32 b, uint4& o0, uint4& o1) {
  o0.x = ((b & 0x0001u) ? 0x3F80u : 0u) | ((b & 0x0002u) ? 0x3F800000u : 0u);
  o0.y = ((b & 0x0004u) ? 0x3F80u : 0u) | ((b & 0x0008u) ? 0x3F800000u : 0u);
  o0.z = ((b & 0x0010u) ? 0x3F80u : 0u) | ((b & 0x0020u) ? 0x3F800000u : 0u);
  o0.w = ((b & 0x0040u) ? 0x3F80u : 0u) | ((b & 0x0080u) ? 0x3F800000u : 0u);
  o1.x = ((b & 0x0100u) ? 0x3F80u : 0u) | ((b & 0x0200u) ? 0x3F800000u : 0u);
  o1.y = ((b & 0x0400u) ? 0x3F80u : 0u) | ((b & 0x0800u) ? 0x3F800000u : 0u);
  o1.z = ((b & 0x1000u) ? 0x3F80u : 0u) | ((b & 0x2000u) ? 0x3F800000u : 0u);
  o1.w = ((b & 0x4000u) ? 0x3F80u : 0u) | ((b & 0x8000u) ? 0x3F800000u : 0u);
}

// 4 waves, each a 64x64 quadrant; 4x4 subtiles of 16x16x32 bf16 MFMA.
#define MFMA_4x4(As_, Bs_, aoff_, boff_)                                         \
  {                                                                              \
    short8 afr[4], bfr[4];                                                       \
    _Pragma("unroll") for (int i_ = 0; i_ < 4; ++i_)                             \
      afr[i_] = *(const short8*)(As_ + aoff_[i_]);                               \
    _Pragma("unroll") for (int j_ = 0; j_ < 4; ++j_)                             \
      bfr[j_] = *(const short8*)(Bs_ + boff_[j_]);                               \
    _Pragma("unroll") for (int i_ = 0; i_ < 4; ++i_)                             \
      _Pragma("unroll") for (int j_ = 0; j_ < 4; ++j_)                           \
        acc[i_][j_] = __builtin_amdgcn_mfma_f32_16x16x32_bf16(                   \
            afr[i_], bfr[j_], acc[i_][j_], 0, 0, 0);                             \
  }

#define ZERO_ACC()                                                               \
  f32x4 acc[4][4];                                                               \
  {                                                                              \
    const f32x4 fz = {0.f, 0.f, 0.f, 0.f};                                       \
    _Pragma("unroll") for (int i_ = 0; i_ < 4; ++i_)                             \
      _Pragma("unroll") for (int j_ = 0; j_ < 4; ++j_) acc[i_][j_] = fz;         \
  }

// ---------------------------------------------------------------------------
// PREP: Ft via coalesced LDS-tile transpose; K1T/K2T gathers; params->fp32;
// zero deg + BN stats. (289 blocks, no adj access.)
// Ft:  [256 k0][128 f][32 p]  K1T: [4 k0][256 c][32 f]  K2T: [8 k0][128 c][32 f]
// ---------------------------------------------------------------------------
__global__ void k_prep(const void* __restrict__ featv, const void* __restrict__ K1v,
                       const void* __restrict__ K2v,
                       const void* __restrict__ b1v, const void* __restrict__ g1v,
                       const void* __restrict__ be1v, const void* __restrict__ b2v,
                       const void* __restrict__ g2v, const void* __restrict__ be2v,
                       u16* __restrict__ Ft, u16* __restrict__ K1T, u16* __restrict__ K2T,
                       float* __restrict__ deg, float* __restrict__ par,
                       float* __restrict__ bn1s, float* __restrict__ bn1q,
                       float* __restrict__ bn2s, float* __restrict__ bn2q) {
  const int b = blockIdx.x, t = threadIdx.x;
  const int flag = dvote((const u16*)featv);
  if (b < 256) {
    __shared__ __align__(16) u16 Lf[32 * 136];
    const int pr = t >> 3, ck = t & 7;
    u16 v[16];
    if (flag) {
      const u16* s = (const u16*)featv + (size_t)(b * 32 + pr) * 128 + ck * 16;
      *(uint4*)&v[0] = *(const uint4*)(s);
      *(uint4*)&v[8] = *(const uint4*)(s + 8);
    } else {
      const float* s = (const float*)featv + (size_t)(b * 32 + pr) * 128 + ck * 16;
#pragma unroll
      for (int i = 0; i < 16; ++i) v[i] = f2b(s[i]);
    }
    *(uint4*)(Lf + pr * 136 + ck * 16) = *(uint4*)&v[0];
    *(uint4*)(Lf + pr * 136 + ck * 16 + 8) = *(uint4*)&v[8];
    __syncthreads();
    const int f = t >> 1, h16 = (t & 1) * 16;
    u32 w[8];
#pragma unroll
    for (int i = 0; i < 8; ++i) {
      u16 lo = Lf[(h16 + 2 * i) * 136 + f];
      u16 hi = Lf[(h16 + 2 * i + 1) * 136 + f];
      w[i] = (u32)lo | ((u32)hi << 16);
    }
    u16* d = Ft + (size_t)b * 4096 + f * 32 + h16;
    *(uint4*)(d) = *(uint4*)&w[0];
    *(uint4*)(d + 8) = *(uint4*)&w[4];
  } else if (b < 272) {
    int o = ((b - 256) * 256 + t) << 3;
    int k0 = o >> 13, c = (o >> 5) & 255, kk = o & 31;
    uint4 w;
    if (flag) {
      const u16* s = (const u16*)K1v + (size_t)(k0 * 32 + kk) * 256 + c;
      w.x = (u32)s[0]    | ((u32)s[256]  << 16);
      w.y = (u32)s[512]  | ((u32)s[768]  << 16);
      w.z = (u32)s[1024] | ((u32)s[1280] << 16);
      w.w = (u32)s[1536] | ((u32)s[1792] << 16);
    } else {
      const float* s = (const float*)K1v + (size_t)(k0 * 32 + kk) * 256 + c;
      w.x = pkf(s[0], s[256]); w.y = pkf(s[512], s[768]);
      w.z = pkf(s[1024], s[1280]); w.w = pkf(s[1536], s[1792]);
    }
    *(uint4*)(K1T + o) = w;
  } else if (b < 288) {
    int o = ((b - 272) * 256 + t) << 3;
    int k0 = o >> 12, c = (o >> 5) & 127, kk = o & 31;
    uint4 w;
    if (flag) {
      const u16* s = (const u16*)K2v + (size_t)(k0 * 32 + kk) * 128 + c;
      w.x = (u32)s[0]   | ((u32)s[128] << 16);
      w.y = (u32)s[256] | ((u32)s[384] << 16);
      w.z = (u32)s[512] | ((u32)s[640] << 16);
      w.w = (u32)s[768] | ((u32)s[896] << 16);
    } else {
      const float* s = (const float*)K2v + (size_t)(k0 * 32 + kk) * 128 + c;
      w.x = pkf(s[0], s[128]); w.y = pkf(s[256], s[384]);
      w.z = pkf(s[512], s[640]); w.w = pkf(s[768], s[896]);
    }
    *(uint4*)(K2T + o) = w;
  } else {
    if (t < 256) {
      par[t]       = flag ? b2f(((const u16*)b1v)[t])  : ((const float*)b1v)[t];
      par[256 + t] = flag ? b2f(((const u16*)g1v)[t])  : ((const float*)g1v)[t];
      par[512 + t] = flag ? b2f(((const u16*)be1v)[t]) : ((const float*)be1v)[t];
      bn1s[t] = 0.f; bn1q[t] = 0.f;
    }
    if (t < 128) {
      par[768 + t]  = flag ? b2f(((const u16*)b2v)[t])  : ((const float*)b2v)[t];
      par[896 + t]  = flag ? b2f(((const u16*)g2v)[t])  : ((const float*)g2v)[t];
      par[1024 + t] = flag ? b2f(((const u16*)be2v)[t]) : ((const float*)be2v)[t];
      bn2s[t] = 0.f; bn2q[t] = 0.f;
    }
    for (int i = t; i < N8K; i += 256) deg[i] = 0.f;
  }
}

// ---------------------------------------------------------------------------
// GEMM1 (BK=128, adj register-prefetch): C[m=f][n=r] = sum_p Ft[f][p]*adj[p][r].
// grid 64 nt x 8 splits, 8 iters of 128-K. Iter ks+1's 16 adj int4 are issued
// during iter ks's MFMA phase (loads in flight across the barrier). A(Ft) via
// 8x global_load_lds; deg free; RB rowbits via shuffle-OR.
// Out P1h[s][r][128 f] fp16.
// ---------------------------------------------------------------------------
__global__ __launch_bounds__(256, 2)
void k_gemm1(const int* __restrict__ adj, const u16* __restrict__ Ft,
             u16* __restrict__ P1h, float* __restrict__ deg,
             u32* __restrict__ RB) {
  __shared__ __align__(16) u16 As[4 * 128 * 32];
  __shared__ __align__(16) u16 Bs[4 * 128 * 32];
  __shared__ float degp[128];
  const int t = threadIdx.x, bx = blockIdx.x;
  const int nt = bx & 63, s = bx >> 6;
  const int n0 = nt << 7;
  const int lane = t & 63, wv = t >> 6;
  const int wm = (wv & 1) << 6, wn = (wv >> 1) << 6;
  const int fm = lane & 15, fq = lane >> 4;
  if (t < 128) degp[t] = 0.0f;
  ZERO_ACC();
  int aoff[4], boff[4];
#pragma unroll
  for (int i = 0; i < 4; ++i) aoff[i] = (wm + i * 16 + fm) * 32 + fq * 8;
#pragma unroll
  for (int j = 0; j < 4; ++j) {
    int n = wn + j * 16 + fm;
    boff[j] = n * 32 + ((fq * 8) ^ (((n >> 2) & 3) << 3));
  }
  const int rb = t & 31, kb = t >> 5;
  const int* gB = adj + ((size_t)s * 1024 + kb * 4) * N8K + n0 + rb * 4;
  const char* gA = (const char*)(Ft + (size_t)s * 32 * 4096);
  char* lA = (char*)As + ((t >> 6) << 10);
  const int goff = t << 4;
  u16* lb0 = Bs + (rb * 4) * 32 + ((kb * 4) ^ ((rb & 3) << 3));
  const int sh4 = (rb & 7) * 4;
  const int rbw = (n0 >> 5) + (rb >> 3);
  const int pb0 = s * 1024 + kb * 4;
  int ds0 = 0, ds1 = 0, ds2 = 0, ds3 = 0;
  int4 pa[16];
  // prologue: load iter 0's adj block
#pragma unroll
  for (int ph = 0; ph < 4; ++ph) {
    const int* g = gB + (size_t)ph * 32 * N8K;
    pa[ph * 4 + 0] = *(const int4*)(g);
    pa[ph * 4 + 1] = *(const int4*)(g + N8K);
    pa[ph * 4 + 2] = *(const int4*)(g + 2 * N8K);
    pa[ph * 4 + 3] = *(const int4*)(g + 3 * N8K);
  }
  gB += 128 * N8K;
#pragma unroll 1
  for (int ks = 0; ks < 8; ++ks) {
    __syncthreads();
#pragma unroll
    for (int ph = 0; ph < 8; ++ph) gl_lds16(gA + ph * 4096 + goff, lA + ph * 4096);
    gA += 32768;
    u32* dst = RB + (size_t)(pb0 + ks * 128) * 256 + rbw;
#pragma unroll
    for (int ph = 0; ph < 4; ++ph) {
      int4 a0 = pa[ph * 4 + 0];
      int4 a1 = pa[ph * 4 + 1];
      int4 a2 = pa[ph * 4 + 2];
      int4 a3 = pa[ph * 4 + 3];
      ds0 += a0.x + a1.x + a2.x + a3.x;
      ds1 += a0.y + a1.y + a2.y + a3.y;
      ds2 += a0.z + a1.z + a2.z + a3.z;
      ds3 += a0.w + a1.w + a2.w + a3.w;
      u16* lb = lb0 + ph * 4096;
      uint2 w;
      w.x = pk01(a0.x, a1.x); w.y = pk01(a2.x, a3.x); *(uint2*)(lb) = w;
      w.x = pk01(a0.y, a1.y); w.y = pk01(a2.y, a3.y); *(uint2*)(lb + 32) = w;
      w.x = pk01(a0.z, a1.z); w.y = pk01(a2.z, a3.z); *(uint2*)(lb + 64) = w;
      w.x = pk01(a0.w, a1.w); w.y = pk01(a2.w, a3.w); *(uint2*)(lb + 96) = w;
      u32 v0 = ((u32)a0.x | ((u32)a0.y << 1) | ((u32)a0.z << 2) | ((u32)a0.w << 3)) << sh4;
      u32 v1 = ((u32)a1.x | ((u32)a1.y << 1) | ((u32)a1.z << 2) | ((u32)a1.w << 3)) << sh4;
      u32 v2 = ((u32)a2.x | ((u32)a2.y << 1) | ((u32)a2.z << 2) | ((u32)a2.w << 3)) << sh4;
      u32 v3 = ((u32)a3.x | ((u32)a3.y << 1) | ((u32)a3.z << 2) | ((u32)a3.w << 3)) << sh4;
      v0 |= __shfl_xor(v0, 1); v0 |= __shfl_xor(v0, 2); v0 |= __shfl_xor(v0, 4);
      v1 |= __shfl_xor(v1, 1); v1 |= __shfl_xor(v1, 2); v1 |= __shfl_xor(v1, 4);
      v2 |= __shfl_xor(v2, 1); v2 |= __shfl_xor(v2, 2); v2 |= __shfl_xor(v2, 4);
      v3 |= __shfl_xor(v3, 1); v3 |= __shfl_xor(v3, 2); v3 |= __shfl_xor(v3, 4);
      if ((rb & 7) == 0) {
        u32* d2 = dst + ph * 8192;
        d2[0] = v0; d2[256] = v1; d2[512] = v2; d2[768] = v3;
      }
    }
    __syncthreads();
    // prefetch next iter's adj during the MFMA phase
    if (ks < 7) {
#pragma unroll
      for (int ph = 0; ph < 4; ++ph) {
        const int* g = gB + (size_t)ph * 32 * N8K;
        pa[ph * 4 + 0] = *(const int4*)(g);
        pa[ph * 4 + 1] = *(const int4*)(g + N8K);
        pa[ph * 4 + 2] = *(const int4*)(g + 2 * N8K);
        pa[ph * 4 + 3] = *(const int4*)(g + 3 * N8K);
      }
      gB += 128 * N8K;
    }
#pragma unroll
    for (int ph = 0; ph < 4; ++ph)
      MFMA_4x4((As + ph * 4096), (Bs + ph * 4096), aoff, boff);
  }
  atomicAdd(&degp[rb * 4 + 0], (float)ds0);
  atomicAdd(&degp[rb * 4 + 1], (float)ds1);
  atomicAdd(&degp[rb * 4 + 2], (float)ds2);
  atomicAdd(&degp[rb * 4 + 3], (float)ds3);
  u16* base = P1h + ((size_t)s * N8K + n0) * 128;
#pragma unroll
  for (int i = 0; i < 4; ++i)
#pragma unroll
    for (int j = 0; j < 4; ++j) {
      int r = wn + j * 16 + fm;
      int f = wm + i * 16 + fq * 4;
      uint2 w;
      w.x = pkh(acc[i][j][0], acc[i][j][1]);
      w.y = pkh(acc[i][j][2], acc[i][j][3]);
      *(uint2*)(base + (size_t)r * 128 + f) = w;
    }
  __syncthreads();
  if (t < 128) atomicAdd(&deg[n0 + t], degp[t]);
}

// ---------------------------------------------------------------------------
// PROJF1 (BM=64): region1b = bf16( (sum_s P1h * invdeg) @ K1 + b1 ), fused BN1
// stats. grid 256 = 128 mt x 2 ct.
// ---------------------------------------------------------------------------
__global__ __launch_bounds__(256, 2)
void k_projf(const u16* __restrict__ P1h, const float* __restrict__ deg,
             const u16* __restrict__ K1T, const float* __restrict__ bias,
             u16* __restrict__ region1b, float* __restrict__ bns, float* __restrict__ bnq) {
  __shared__ __align__(16) u16 As[64 * 32];
  __shared__ __align__(16) u16 Bs[128 * 32];
  const int t = threadIdx.x, bx = blockIdx.x;
  const int ct = bx & 1, mt = bx >> 1;
  const int m0 = mt << 6, n0 = ct << 7;
  const int lane = t & 63, wv = t >> 6;
  const int wn = wv << 5;
  const int fm = lane & 15, fq = lane >> 4;
  const f32x4 fz = {0.f, 0.f, 0.f, 0.f};
  f32x4 acc[4][2];
#pragma unroll
  for (int i = 0; i < 4; ++i)
#pragma unroll
    for (int j = 0; j < 2; ++j) acc[i][j] = fz;
  int aoff[4], boff[2];
#pragma unroll
  for (int i = 0; i < 4; ++i) {
    int m = i * 16 + fm;
    aoff[i] = m * 32 + ((fq * 8) ^ (((m >> 2) & 3) << 3));
  }
#pragma unroll
  for (int j = 0; j < 2; ++j) boff[j] = (wn + j * 16 + fm) * 32 + fq * 8;
  const int row = t >> 2, q = t & 3;
  const u16* src = P1h + (size_t)(m0 + row) * 128 + q * 8;
  float d = deg[m0 + row];
  const float inv = (d > 0.5f) ? 1.0f / d : 0.0f;
  const int swz = ((row >> 2) & 3) << 3;
  u16* la = As + row * 32 + ((q * 8) ^ swz);
  char* lB = (char*)Bs + ((t >> 6) << 10);
  const int goff = t << 4;
  for (int ks = 0; ks < 4; ++ks) {
    __syncthreads();
    const char* gB = (const char*)(K1T + ((size_t)ks * 256 + n0) * 32);
    gl_lds16(gB + goff, lB);
    gl_lds16(gB + 4096 + goff, lB + 4096);
    f32x4 s0 = fz, s1 = fz;
    const u16* p = src + ks * 32;
#pragma unroll
    for (int sp = 0; sp < 8; ++sp) {
      H8 L;
      L.u = *(const uint4*)(p + (size_t)sp * N8K * 128);
#pragma unroll
      for (int jj = 0; jj < 4; ++jj) {
        s0[jj] += (float)L.h[jj];
        s1[jj] += (float)L.h[4 + jj];
      }
    }
    s0 *= inv; s1 *= inv;
    uint4 w;
    w.x = pkf(s0[0], s0[1]); w.y = pkf(s0[2], s0[3]);
    w.z = pkf(s1[0], s1[1]); w.w = pkf(s1[2], s1[3]);
    *(uint4*)la = w;
    __syncthreads();
    short8 afr[4], bfr[2];
#pragma unroll
    for (int i = 0; i < 4; ++i) afr[i] = *(const short8*)(As + aoff[i]);
#pragma unroll
    for (int j = 0; j < 2; ++j) bfr[j] = *(const short8*)(Bs + boff[j]);
#pragma unroll
    for (int i = 0; i < 4; ++i)
#pragma unroll
      for (int j = 0; j < 2; ++j)
        acc[i][j] = __builtin_amdgcn_mfma_f32_16x16x32_bf16(afr[i], bfr[j], acc[i][j], 0, 0, 0);
  }
#pragma unroll
  for (int j = 0; j < 2; ++j) {
    int c = n0 + wn + j * 16 + fm;
    float bc = bias[c];
    float t1 = 0.f, t2 = 0.f;
#pragma unroll
    for (int i = 0; i < 4; ++i) {
      int r = m0 + i * 16 + fq * 4;
#pragma unroll
      for (int ii = 0; ii < 4; ++ii) {
        float v = acc[i][j][ii] + bc;
        region1b[(size_t)(r + ii) * 256 + c] = f2b(v);
        t1 += v; t2 += v * v;
      }
    }
    t1 += __shfl_xor(t1, 16); t1 += __shfl_xor(t1, 32);
    t2 += __shfl_xor(t2, 16); t2 += __shfl_xor(t2, 32);
    if (fq == 0) { atomicAdd(&bns[c], t1); atomicAdd(&bnq[c], t2); }
  }
}

// ---------------------------------------------------------------------------
// BNH (BM=32): H = (BN1(region1b)*invdeg) @ K2. grid 256 (1 block/CU).
// region1b is bf16. Writes HT[r/32][128][r&31] bf16.
// ---------------------------------------------------------------------------
__global__ __launch_bounds__(256, 2)
void k_bnH(const u16* __restrict__ region1b, const float* __restrict__ deg,
           const float* __restrict__ bn1s, const float* __restrict__ bn1q,
           const float* __restrict__ g1, const float* __restrict__ be1,
           const u16* __restrict__ K2T, u16* __restrict__ HT) {
  __shared__ __align__(16) u16 As[32 * 32];
  __shared__ __align__(16) u16 Bs[128 * 32];
  __shared__ float scS[256], shS[256];
  const int t = threadIdx.x, mt = blockIdx.x;
  const int m0 = mt << 5;
  const int lane = t & 63, wv = t >> 6;
  const int wn = wv << 5;
  const int fm = lane & 15, fq = lane >> 4;
  {
    float mu = bn1s[t] * (1.0f / 8192.0f);
    float var = bn1q[t] * (1.0f / 8192.0f) - mu * mu;
    float iv = rsqrtf(var + 1e-3f);
    float sc = iv * g1[t];
    scS[t] = sc;
    shS[t] = be1[t] - mu * sc;
  }
  const f32x4 fz = {0.f, 0.f, 0.f, 0.f};
  f32x4 acc[2][2];
#pragma unroll
  for (int i = 0; i < 2; ++i)
#pragma unroll
    for (int j = 0; j < 2; ++j) acc[i][j] = fz;
  int aoff[2], boff[2];
#pragma unroll
  for (int i = 0; i < 2; ++i) {
    int m = i * 16 + fm;
    aoff[i] = m * 32 + ((fq * 8) ^ (((m >> 2) & 3) << 3));
  }
#pragma unroll
  for (int j = 0; j < 2; ++j) boff[j] = (wn + j * 16 + fm) * 32 + fq * 8;
  const int row = t >> 3, oct = t & 7;
  float d = deg[m0 + row];
  const float idg = (d > 0.5f) ? 1.0f / d : 0.0f;
  const u16* src = region1b + (size_t)(m0 + row) * 256 + oct * 4;
  const int swz = ((row >> 2) & 3) << 3;
  u16* la = As + row * 32 + ((oct * 4) ^ swz);
  char* lB = (char*)Bs + ((t >> 6) << 10);
  const int goff = t << 4;
  for (int ks = 0; ks < 8; ++ks) {
    __syncthreads();
    const char* gB = (const char*)(K2T + (size_t)ks * 4096);
    gl_lds16(gB + goff, lB);
    gl_lds16(gB + 4096 + goff, lB + 4096);
    const int cb = ks * 32 + oct * 4;
    uint2 xw = *(const uint2*)(src + ks * 32);
    float x0 = b2f((u16)(xw.x & 0xFFFFu)), x1 = b2f((u16)(xw.x >> 16));
    float x2 = b2f((u16)(xw.y & 0xFFFFu)), x3 = b2f((u16)(xw.y >> 16));
    float y0 = (x0 * scS[cb + 0] + shS[cb + 0]) * idg;
    float y1 = (x1 * scS[cb + 1] + shS[cb + 1]) * idg;
    float y2 = (x2 * scS[cb + 2] + shS[cb + 2]) * idg;
    float y3 = (x3 * scS[cb + 3] + shS[cb + 3]) * idg;
    uint2 w;
    w.x = pkf(y0, y1);
    w.y = pkf(y2, y3);
    *(uint2*)la = w;
    __syncthreads();
    short8 afr[2], bfr[2];
#pragma unroll
    for (int i = 0; i < 2; ++i) afr[i] = *(const short8*)(As + aoff[i]);
#pragma unroll
    for (int j = 0; j < 2; ++j) bfr[j] = *(const short8*)(Bs + boff[j]);
#pragma unroll
    for (int i = 0; i < 2; ++i)
#pragma unroll
      for (int j = 0; j < 2; ++j)
        acc[i][j] = __builtin_amdgcn_mfma_f32_16x16x32_bf16(afr[i], bfr[j], acc[i][j], 0, 0, 0);
  }
#pragma unroll
  for (int i = 0; i < 2; ++i)
#pragma unroll
    for (int j = 0; j < 2; ++j) {
      int c = wn + j * 16 + fm;
      int r = m0 + i * 16 + fq * 4;
      uint2 w;
      w.x = pkf(acc[i][j][0], acc[i][j][1]);
      w.y = pkf(acc[i][j][2], acc[i][j][3]);
      *(uint2*)(HT + (size_t)(r >> 5) * 4096 + c * 32 + (r & 31)) = w;
    }
}

// ---------------------------------------------------------------------------
// GEMM2 (BK=128, RB register-prefetch): C[m=p][n=c] = sum_r adj[p][r]*H[r][c].
// grid 64 mt x 8 splits. A from RB rowbits (prefetched uint4 -> unpack16 ->
// swizzled LDS); B(HT) via 8x global_load_lds. Out P2h[s][p][128 c] fp16.
// ---------------------------------------------------------------------------
__global__ __launch_bounds__(256, 2)
void k_gemm2(const u32* __restrict__ RB, const u16* __restrict__ HT,
             u16* __restrict__ P2h) {
  __shared__ __align__(16) u16 As[4 * 128 * 32];
  __shared__ __align__(16) u16 Bs[4 * 128 * 32];
  const int t = threadIdx.x, bx = blockIdx.x;
  const int mt = bx & 63, s = bx >> 6;
  const int m0 = mt << 7;
  const int lane = t & 63, wv = t >> 6;
  const int wm = (wv & 1) << 6, wn = (wv >> 1) << 6;
  const int fm = lane & 15, fq = lane >> 4;
  ZERO_ACC();
  int aoff[4], boff[4];
#pragma unroll
  for (int i = 0; i < 4; ++i) {
    int m = wm + i * 16 + fm;
    aoff[i] = m * 32 + ((fq * 8) ^ (((m >> 2) & 3) << 3));
  }
#pragma unroll
  for (int j = 0; j < 4; ++j) boff[j] = (wn + j * 16 + fm) * 32 + fq * 8;
  const int row = t >> 1, h = t & 1;
  const u32* gA = RB + (size_t)(m0 + row) * 256 + s * 32;
  const char* gB = (const char*)(HT + (size_t)s * 32 * 4096);
  char* lB = (char*)Bs + ((t >> 6) << 10);
  const int goff = t << 4;
  const int swzA = ((row >> 2) & 3) << 3;
  u16* la0 = As + row * 32 + ((h * 16) ^ swzA);
  u16* la1 = As + row * 32 + (((h * 16) + 8) ^ swzA);
  uint4 wcur = *(const uint4*)(gA);
#pragma unroll 1
  for (int ks = 0; ks < 8; ++ks) {
    __syncthreads();
#pragma unroll
    for (int ph = 0; ph < 8; ++ph) gl_lds16(gB + ph * 4096 + goff, lB + ph * 4096);
    gB += 32768;
    u32 ws[4] = {wcur.x, wcur.y, wcur.z, wcur.w};
#pragma unroll
    for (int ph = 0; ph < 4; ++ph) {
      u32 bits = (ws[ph] >> (h * 16)) & 0xFFFFu;
      uint4 o0, o1;
      unpack16(bits, o0, o1);
      *(uint4*)(la0 + ph * 4096) = o0;
      *(uint4*)(la1 + ph * 4096) = o1;
    }
    __syncthreads();
    if (ks < 7) wcur = *(const uint4*)(gA + (ks + 1) * 4);
#pragma unroll
    for (int ph = 0; ph < 4; ++ph)
      MFMA_4x4((As + ph * 4096), (Bs + ph * 4096), aoff, boff);
  }
  u16* base = P2h + (size_t)s * N8K * 128;
#pragma unroll
  for (int i = 0; i < 4; ++i)
#pragma unroll
    for (int j = 0; j < 4; ++j) {
      int c = wn + j * 16 + fm;
      int pr = m0 + wm + i * 16 + fq * 4;
#pragma unroll
      for (int ii = 0; ii < 4; ++ii)
        base[(size_t)(pr + ii) * 128 + c] = f2h(acc[i][j][ii]);
    }
}

// ---------------------------------------------------------------------------
// RED2: people1 = sum_s P2h + b2, fused BN2 sum/sumsq stats. Paired-column
// u32 fp16 loads; float2 stores.
// ---------------------------------------------------------------------------
__global__ void k_red2(const u16* __restrict__ P2h, const float* __restrict__ bias,
                       float* __restrict__ people1,
                       float* __restrict__ bn2s, float* __restrict__ bn2q) {
  __shared__ float r1[512], r2[512];
  const int t = threadIdx.x;
  const int c = (t & 63) * 2, pg = t >> 6;
  const int p0 = blockIdx.x << 5;
  const float bc0 = bias[c], bc1 = bias[c + 1];
  float s1a = 0.f, s2a = 0.f, s1b = 0.f, s2b = 0.f;
  for (int pp = pg; pp < 32; pp += 4) {
    size_t o = (size_t)(p0 + pp) * 128 + c;
    float v0 = bc0, v1 = bc1;
#pragma unroll
    for (int s = 0; s < 8; ++s) {
      H2 L;
      L.u = *(const u32*)(P2h + (size_t)s * N8K * 128 + o);
      v0 += (float)L.h[0];
      v1 += (float)L.h[1];
    }
    float2 st; st.x = v0; st.y = v1;
    *(float2*)(people1 + o) = st;
    s1a += v0; s2a += v0 * v0;
    s1b += v1; s2b += v1 * v1;
  }
  r1[t * 2] = s1a; r1[t * 2 + 1] = s1b;
  r2[t * 2] = s2a; r2[t * 2 + 1] = s2b;
  __syncthreads();
  if (t < 128) {
    float a = 0.f, b = 0.f;
#pragma unroll
    for (int g = 0; g < 4; ++g) {
      int idx = ((t >> 1) + 64 * g) * 2 + (t & 1);
      a += r1[idx]; b += r2[idx];
    }
    atomicAdd(&bn2s[t], a);
    atomicAdd(&bn2q[t], b);
  }
}

// ---------------------------------------------------------------------------
// BN2APPLY: out = BN2(people1); output dtype via per-block vote on feat.
// ---------------------------------------------------------------------------
__global__ void k_bn2apply(const float* __restrict__ people1,
                           const float* __restrict__ bn2s, const float* __restrict__ bn2q,
                           const float* __restrict__ g2, const float* __restrict__ be2,
                           const u16* __restrict__ featprobe, void* __restrict__ outv) {
  const int flag = dvote(featprobe);
  int g = blockIdx.x * 256 + threadIdx.x;
  int p = g >> 5;
  int c = (g & 31) << 2;
  f32x4 x = *(const f32x4*)(people1 + (size_t)p * 128 + c);
  f32x4 y;
#pragma unroll
  for (int jj = 0; jj < 4; ++jj) {
    int cc = c + jj;
    float mu = bn2s[cc] * (1.0f / 8192.0f);
    float var = bn2q[cc] * (1.0f / 8192.0f) - mu * mu;
    float inv = rsqrtf(var + 1e-3f);
    y[jj] = (x[jj] - mu) * inv * g2[cc] + be2[cc];
  }
  if (flag) {
    uint2 w;
    w.x = pkf(y[0], y[1]);
    w.y = pkf(y[2], y[3]);
    *(uint2*)((u16*)outv + (size_t)p * 128 + c) = w;
  } else {
    *(f32x4*)((float*)outv + (size_t)p * 128 + c) = y;
  }
}

// ---------------------------------------------------------------------------
// Workspace (~56.3 MB):
//  [0,16M)   Ph: P1h (8 x 2MB fp16) then P2h (8 x 2MB fp16)
//  [32M,36M) region1b bf16   [40M,44M) people1 fp32
//  [44M,46M) Ft bf16         [46M,48M) HT bf16
//  [48M,56M) RB rowbits u32 (written by gemm1, read by gemm2)
//  [56M,..)  K1T(64K), K2T(64K), deg(32K), par, bn stats
// ---------------------------------------------------------------------------
extern "C" void kernel_launch(void* const* d_in, const int* in_sizes, int n_in,
                              void* d_out, int out_size, void* d_ws, size_t ws_size,
                              hipStream_t stream) {
  const void* feat = d_in[0];
  const int* adj   = (const int*)d_in[1];
  const void* K1   = d_in[2];
  const void* b1   = d_in[3];
  const void* g1   = d_in[4];
  const void* be1  = d_in[5];
  const void* K2   = d_in[6];
  const void* b2   = d_in[7];
  const void* g2   = d_in[8];
  const void* be2  = d_in[9];
  char* ws = (char*)d_ws;
  const size_t MB = 1u << 20;

  u16*   Ph       = (u16*)(ws);
  u16*   region1b = (u16*)(ws + 32 * MB);
  float* people1  = (float*)(ws + 40 * MB);
  u16*   Ft       = (u16*)(ws + 44 * MB);
  u16*   HT       = (u16*)(ws + 46 * MB);
  u32*   RB       = (u32*)(ws + 48 * MB);
  u16*   K1T      = (u16*)(ws + 56 * MB);
  u16*   K2T      = K1T + 32768;
  float* deg      = (float*)(K2T + 32768);
  float* par      = deg + N8K;
  float* bn1s     = par + 1152;
  float* bn1q     = bn1s + 256;
  float* bn2s     = bn1q + 256;
  float* bn2q     = bn2s + 128;

  k_prep<<<289, 256, 0, stream>>>(feat, K1, K2, b1, g1, be1, b2, g2, be2,
                                  Ft, K1T, K2T, deg, par, bn1s, bn1q, bn2s, bn2q);
  k_gemm1<<<512, 256, 0, stream>>>(adj, Ft, Ph, deg, RB);
  k_projf<<<256, 256, 0, stream>>>(Ph, deg, K1T, par + 0, region1b, bn1s, bn1q);
  k_bnH<<<256, 256, 0, stream>>>(region1b, deg, bn1s, bn1q, par + 256, par + 512,
                                 K2T, HT);
  k_gemm2<<<512, 256, 0, stream>>>(RB, HT, Ph);
  k_red2<<<256, 256, 0, stream>>>(Ph, par + 768, people1, bn2s, bn2q);
  k_bn2apply<<<1024, 256, 0, stream>>>(people1, bn2s, bn2q, par + 896, par + 1024,
                                       (const u16*)feat, d_out);
}

// Round 12
// 448.419 us; speedup vs baseline: 1.0080x; 1.0080x over previous
//
#include <hip/hip_runtime.h>
#include <stdint.h>

typedef unsigned int u32;
typedef unsigned short u16;
typedef unsigned long long u64;
typedef __attribute__((ext_vector_type(8))) short short8;
typedef __attribute__((ext_vector_type(4))) float f32x4;

#define N8K 8192

__device__ __forceinline__ float b2f(u16 u) { return __uint_as_float(((u32)u) << 16); }
__device__ __forceinline__ u16 f2b(float f) {
  u32 i = __float_as_uint(f);
  i += 0x7FFFu + ((i >> 16) & 1u);
  return (u16)(i >> 16);
}
// fp16 (RNE) helpers for split-K partials
__device__ __forceinline__ u16 f2h(float f) {
  union { _Float16 h; u16 u; } x; x.h = (_Float16)f; return x.u;
}
__device__ __forceinline__ u32 pkh(float a, float b) {
  return (u32)f2h(a) | ((u32)f2h(b) << 16);
}
union H8 { uint4 u; _Float16 h[8]; };
union H2 { u32 u; _Float16 h[2]; };
// pack two 0/1 ints into two bf16 halves
__device__ __forceinline__ u32 pk01(int x, int y) { return (u32)__mul24(x | (y << 16), 0x3F80); }
__device__ __forceinline__ u32 pkf(float a, float b) { return (u32)f2b(a) | ((u32)f2b(b) << 16); }

// block-uniform dtype vote: 1 = tensors are bf16, 0 = fp32
__device__ __forceinline__ int dvote(const u16* f16) {
  u16 u = f16[threadIdx.x * 2];
  int e = (u >> 7) & 0xFF;
  return __syncthreads_count((e >= 0x60 && e <= 0x9F) ? 1 : 0) >= 128;
}

// async global->LDS, 16B/lane; lds dest wave-uniform base (+lane*16)
__device__ __forceinline__ void gl_lds16(const void* g, void* l) {
  __builtin_amdgcn_global_load_lds(
      (const __attribute__((address_space(1))) u32*)g,
      (__attribute__((address_space(3))) u32*)l, 16, 0, 0);
}

// 16 bits (0/1 adjacency) -> 8 u32 bf16-pairs (1.0f bf16 = 0x3F80)
__device__ __forceinline__ void unpack16(u32 b, uint4& o0, uint4& o1) {
  o0.x = ((b & 0x0001u) ? 0x3F80u : 0u) | ((b & 0x0002u) ? 0x3F800000u : 0u);
  o0.y = ((b & 0x0004u) ? 0x3F80u : 0u) | ((b & 0x0008u) ? 0x3F800000u : 0u);
  o0.z = ((b & 0x0010u) ? 0x3F80u : 0u) | ((b & 0x0020u) ? 0x3F800000u : 0u);
  o0.w = ((b & 0x0040u) ? 0x3F80u : 0u) | ((b & 0x0080u) ? 0x3F800000u : 0u);
  o1.x = ((b & 0x0100u) ? 0x3F80u : 0u) | ((b & 0x0200u) ? 0x3F800000u : 0u);
  o1.y = ((b & 0x0400u) ? 0x3F80u : 0u) | ((b & 0x0800u) ? 0x3F800000u : 0u);
  o1.z = ((b & 0x1000u) ? 0x3F80u : 0u) | ((b & 0x2000u) ? 0x3F800000u : 0u);
  o1.w = ((b & 0x4000u) ? 0x3F80u : 0u) | ((b & 0x8000u) ? 0x3F800000u : 0u);
}

// 4 waves, each a 64x64 quadrant; 4x4 subtiles of 16x16x32 bf16 MFMA.
#define MFMA_4x4(As_, Bs_, aoff_, boff_)                                         \
  {                                                                              \
    short8 afr[4], bfr[4];                                                       \
    _Pragma("unroll") for (int i_ = 0; i_ < 4; ++i_)                             \
      afr[i_] = *(const short8*)(As_ + aoff_[i_]);                               \
    _Pragma("unroll") for (int j_ = 0; j_ < 4; ++j_)                             \
      bfr[j_] = *(const short8*)(Bs_ + boff_[j_]);                               \
    _Pragma("unroll") for (int i_ = 0; i_ < 4; ++i_)                             \
      _Pragma("unroll") for (int j_ = 0; j_ < 4; ++j_)                           \
        acc[i_][j_] = __builtin_amdgcn_mfma_f32_16x16x32_bf16(                   \
            afr[i_], bfr[j_], acc[i_][j_], 0, 0, 0);                             \
  }

#define ZERO_ACC()                                                               \
  f32x4 acc[4][4];                                                               \
  {                                                                              \
    const f32x4 fz = {0.f, 0.f, 0.f, 0.f};                                       \
    _Pragma("unroll") for (int i_ = 0; i_ < 4; ++i_)                             \
      _Pragma("unroll") for (int j_ = 0; j_ < 4; ++j_) acc[i_][j_] = fz;         \
  }

// ---------------------------------------------------------------------------
// PREP: Ft via coalesced LDS-tile transpose; K1T/K2T gathers; params->fp32;
// zero deg + BN stats. (289 blocks, no adj access.)
// Ft:  [256 k0][128 f][32 p]  K1T: [4 k0][256 c][32 f]  K2T: [8 k0][128 c][32 f]
// ---------------------------------------------------------------------------
__global__ void k_prep(const void* __restrict__ featv, const void* __restrict__ K1v,
                       const void* __restrict__ K2v,
                       const void* __restrict__ b1v, const void* __restrict__ g1v,
                       const void* __restrict__ be1v, const void* __restrict__ b2v,
                       const void* __restrict__ g2v, const void* __restrict__ be2v,
                       u16* __restrict__ Ft, u16* __restrict__ K1T, u16* __restrict__ K2T,
                       float* __restrict__ deg, float* __restrict__ par,
                       float* __restrict__ bn1s, float* __restrict__ bn1q,
                       float* __restrict__ bn2s, float* __restrict__ bn2q) {
  const int b = blockIdx.x, t = threadIdx.x;
  const int flag = dvote((const u16*)featv);
  if (b < 256) {
    __shared__ __align__(16) u16 Lf[32 * 136];
    const int pr = t >> 3, ck = t & 7;
    u16 v[16];
    if (flag) {
      const u16* s = (const u16*)featv + (size_t)(b * 32 + pr) * 128 + ck * 16;
      *(uint4*)&v[0] = *(const uint4*)(s);
      *(uint4*)&v[8] = *(const uint4*)(s + 8);
    } else {
      const float* s = (const float*)featv + (size_t)(b * 32 + pr) * 128 + ck * 16;
#pragma unroll
      for (int i = 0; i < 16; ++i) v[i] = f2b(s[i]);
    }
    *(uint4*)(Lf + pr * 136 + ck * 16) = *(uint4*)&v[0];
    *(uint4*)(Lf + pr * 136 + ck * 16 + 8) = *(uint4*)&v[8];
    __syncthreads();
    const int f = t >> 1, h16 = (t & 1) * 16;
    u32 w[8];
#pragma unroll
    for (int i = 0; i < 8; ++i) {
      u16 lo = Lf[(h16 + 2 * i) * 136 + f];
      u16 hi = Lf[(h16 + 2 * i + 1) * 136 + f];
      w[i] = (u32)lo | ((u32)hi << 16);
    }
    u16* d = Ft + (size_t)b * 4096 + f * 32 + h16;
    *(uint4*)(d) = *(uint4*)&w[0];
    *(uint4*)(d + 8) = *(uint4*)&w[4];
  } else if (b < 272) {
    int o = ((b - 256) * 256 + t) << 3;
    int k0 = o >> 13, c = (o >> 5) & 255, kk = o & 31;
    uint4 w;
    if (flag) {
      const u16* s = (const u16*)K1v + (size_t)(k0 * 32 + kk) * 256 + c;
      w.x = (u32)s[0]    | ((u32)s[256]  << 16);
      w.y = (u32)s[512]  | ((u32)s[768]  << 16);
      w.z = (u32)s[1024] | ((u32)s[1280] << 16);
      w.w = (u32)s[1536] | ((u32)s[1792] << 16);
    } else {
      const float* s = (const float*)K1v + (size_t)(k0 * 32 + kk) * 256 + c;
      w.x = pkf(s[0], s[256]); w.y = pkf(s[512], s[768]);
      w.z = pkf(s[1024], s[1280]); w.w = pkf(s[1536], s[1792]);
    }
    *(uint4*)(K1T + o) = w;
  } else if (b < 288) {
    int o = ((b - 272) * 256 + t) << 3;
    int k0 = o >> 12, c = (o >> 5) & 127, kk = o & 31;
    uint4 w;
    if (flag) {
      const u16* s = (const u16*)K2v + (size_t)(k0 * 32 + kk) * 128 + c;
      w.x = (u32)s[0]   | ((u32)s[128] << 16);
      w.y = (u32)s[256] | ((u32)s[384] << 16);
      w.z = (u32)s[512] | ((u32)s[640] << 16);
      w.w = (u32)s[768] | ((u32)s[896] << 16);
    } else {
      const float* s = (const float*)K2v + (size_t)(k0 * 32 + kk) * 128 + c;
      w.x = pkf(s[0], s[128]); w.y = pkf(s[256], s[384]);
      w.z = pkf(s[512], s[640]); w.w = pkf(s[768], s[896]);
    }
    *(uint4*)(K2T + o) = w;
  } else {
    if (t < 256) {
      par[t]       = flag ? b2f(((const u16*)b1v)[t])  : ((const float*)b1v)[t];
      par[256 + t] = flag ? b2f(((const u16*)g1v)[t])  : ((const float*)g1v)[t];
      par[512 + t] = flag ? b2f(((const u16*)be1v)[t]) : ((const float*)be1v)[t];
      bn1s[t] = 0.f; bn1q[t] = 0.f;
    }
    if (t < 128) {
      par[768 + t]  = flag ? b2f(((const u16*)b2v)[t])  : ((const float*)b2v)[t];
      par[896 + t]  = flag ? b2f(((const u16*)g2v)[t])  : ((const float*)g2v)[t];
      par[1024 + t] = flag ? b2f(((const u16*)be2v)[t]) : ((const float*)be2v)[t];
      bn2s[t] = 0.f; bn2q[t] = 0.f;
    }
    for (int i = t; i < N8K; i += 256) deg[i] = 0.f;
  }
}

// ---------------------------------------------------------------------------
// GEMM1 (BK=128, R10 version — no register prefetch): C[m=f][n=r] =
// sum_p Ft[f][p]*adj[p][r]. grid 64 nt x 8 splits, 8 iters of 128-K.
// A(Ft) via 8x global_load_lds; B: 16x adj int4 -> pk01 -> swizzled LDS.
// deg free; RB rowbits emitted via shuffle-OR. Out P1h[s][r][128 f] fp16.
// ---------------------------------------------------------------------------
__global__ __launch_bounds__(256, 2)
void k_gemm1(const int* __restrict__ adj, const u16* __restrict__ Ft,
             u16* __restrict__ P1h, float* __restrict__ deg,
             u32* __restrict__ RB) {
  __shared__ __align__(16) u16 As[4 * 128 * 32];
  __shared__ __align__(16) u16 Bs[4 * 128 * 32];
  __shared__ float degp[128];
  const int t = threadIdx.x, bx = blockIdx.x;
  const int nt = bx & 63, s = bx >> 6;
  const int n0 = nt << 7;
  const int lane = t & 63, wv = t >> 6;
  const int wm = (wv & 1) << 6, wn = (wv >> 1) << 6;
  const int fm = lane & 15, fq = lane >> 4;
  if (t < 128) degp[t] = 0.0f;
  ZERO_ACC();
  int aoff[4], boff[4];
#pragma unroll
  for (int i = 0; i < 4; ++i) aoff[i] = (wm + i * 16 + fm) * 32 + fq * 8;
#pragma unroll
  for (int j = 0; j < 4; ++j) {
    int n = wn + j * 16 + fm;
    boff[j] = n * 32 + ((fq * 8) ^ (((n >> 2) & 3) << 3));
  }
  const int rb = t & 31, kb = t >> 5;
  const int* gB = adj + ((size_t)s * 1024 + kb * 4) * N8K + n0 + rb * 4;
  const char* gA = (const char*)(Ft + (size_t)s * 32 * 4096);
  char* lA = (char*)As + ((t >> 6) << 10);
  const int goff = t << 4;
  u16* lb0 = Bs + (rb * 4) * 32 + ((kb * 4) ^ ((rb & 3) << 3));
  const int sh4 = (rb & 7) * 4;
  const int rbw = (n0 >> 5) + (rb >> 3);
  const int pb0 = s * 1024 + kb * 4;
  int ds0 = 0, ds1 = 0, ds2 = 0, ds3 = 0;
  for (int ks = 0; ks < 8; ++ks) {
    __syncthreads();
#pragma unroll
    for (int ph = 0; ph < 8; ++ph) gl_lds16(gA + ph * 4096 + goff, lA + ph * 4096);
    gA += 32768;
    u32* dst = RB + (size_t)(pb0 + ks * 128) * 256 + rbw;
#pragma unroll
    for (int ph = 0; ph < 4; ++ph) {
      const int* g = gB + (size_t)ph * 32 * N8K;
      int4 a0 = *(const int4*)(g);
      int4 a1 = *(const int4*)(g + N8K);
      int4 a2 = *(const int4*)(g + 2 * N8K);
      int4 a3 = *(const int4*)(g + 3 * N8K);
      ds0 += a0.x + a1.x + a2.x + a3.x;
      ds1 += a0.y + a1.y + a2.y + a3.y;
      ds2 += a0.z + a1.z + a2.z + a3.z;
      ds3 += a0.w + a1.w + a2.w + a3.w;
      u16* lb = lb0 + ph * 4096;
      uint2 w;
      w.x = pk01(a0.x, a1.x); w.y = pk01(a2.x, a3.x); *(uint2*)(lb) = w;
      w.x = pk01(a0.y, a1.y); w.y = pk01(a2.y, a3.y); *(uint2*)(lb + 32) = w;
      w.x = pk01(a0.z, a1.z); w.y = pk01(a2.z, a3.z); *(uint2*)(lb + 64) = w;
      w.x = pk01(a0.w, a1.w); w.y = pk01(a2.w, a3.w); *(uint2*)(lb + 96) = w;
      u32 v0 = ((u32)a0.x | ((u32)a0.y << 1) | ((u32)a0.z << 2) | ((u32)a0.w << 3)) << sh4;
      u32 v1 = ((u32)a1.x | ((u32)a1.y << 1) | ((u32)a1.z << 2) | ((u32)a1.w << 3)) << sh4;
      u32 v2 = ((u32)a2.x | ((u32)a2.y << 1) | ((u32)a2.z << 2) | ((u32)a2.w << 3)) << sh4;
      u32 v3 = ((u32)a3.x | ((u32)a3.y << 1) | ((u32)a3.z << 2) | ((u32)a3.w << 3)) << sh4;
      v0 |= __shfl_xor(v0, 1); v0 |= __shfl_xor(v0, 2); v0 |= __shfl_xor(v0, 4);
      v1 |= __shfl_xor(v1, 1); v1 |= __shfl_xor(v1, 2); v1 |= __shfl_xor(v1, 4);
      v2 |= __shfl_xor(v2, 1); v2 |= __shfl_xor(v2, 2); v2 |= __shfl_xor(v2, 4);
      v3 |= __shfl_xor(v3, 1); v3 |= __shfl_xor(v3, 2); v3 |= __shfl_xor(v3, 4);
      if ((rb & 7) == 0) {
        u32* d2 = dst + ph * 8192;
        d2[0] = v0; d2[256] = v1; d2[512] = v2; d2[768] = v3;
      }
    }
    gB += 128 * N8K;
    __syncthreads();
#pragma unroll
    for (int ph = 0; ph < 4; ++ph)
      MFMA_4x4((As + ph * 4096), (Bs + ph * 4096), aoff, boff);
  }
  atomicAdd(&degp[rb * 4 + 0], (float)ds0);
  atomicAdd(&degp[rb * 4 + 1], (float)ds1);
  atomicAdd(&degp[rb * 4 + 2], (float)ds2);
  atomicAdd(&degp[rb * 4 + 3], (float)ds3);
  u16* base = P1h + ((size_t)s * N8K + n0) * 128;
#pragma unroll
  for (int i = 0; i < 4; ++i)
#pragma unroll
    for (int j = 0; j < 4; ++j) {
      int r = wn + j * 16 + fm;
      int f = wm + i * 16 + fq * 4;
      uint2 w;
      w.x = pkh(acc[i][j][0], acc[i][j][1]);
      w.y = pkh(acc[i][j][2], acc[i][j][3]);
      *(uint2*)(base + (size_t)r * 128 + f) = w;
    }
  __syncthreads();
  if (t < 128) atomicAdd(&deg[n0 + t], degp[t]);
}

// ---------------------------------------------------------------------------
// PROJF1 (BM=64): region1b = bf16( (sum_s P1h * invdeg) @ K1 + b1 ), fused BN1
// stats. grid 256 = 128 mt x 2 ct.
// ---------------------------------------------------------------------------
__global__ __launch_bounds__(256, 2)
void k_projf(const u16* __restrict__ P1h, const float* __restrict__ deg,
             const u16* __restrict__ K1T, const float* __restrict__ bias,
             u16* __restrict__ region1b, float* __restrict__ bns, float* __restrict__ bnq) {
  __shared__ __align__(16) u16 As[64 * 32];
  __shared__ __align__(16) u16 Bs[128 * 32];
  const int t = threadIdx.x, bx = blockIdx.x;
  const int ct = bx & 1, mt = bx >> 1;
  const int m0 = mt << 6, n0 = ct << 7;
  const int lane = t & 63, wv = t >> 6;
  const int wn = wv << 5;
  const int fm = lane & 15, fq = lane >> 4;
  const f32x4 fz = {0.f, 0.f, 0.f, 0.f};
  f32x4 acc[4][2];
#pragma unroll
  for (int i = 0; i < 4; ++i)
#pragma unroll
    for (int j = 0; j < 2; ++j) acc[i][j] = fz;
  int aoff[4], boff[2];
#pragma unroll
  for (int i = 0; i < 4; ++i) {
    int m = i * 16 + fm;
    aoff[i] = m * 32 + ((fq * 8) ^ (((m >> 2) & 3) << 3));
  }
#pragma unroll
  for (int j = 0; j < 2; ++j) boff[j] = (wn + j * 16 + fm) * 32 + fq * 8;
  const int row = t >> 2, q = t & 3;
  const u16* src = P1h + (size_t)(m0 + row) * 128 + q * 8;
  float d = deg[m0 + row];
  const float inv = (d > 0.5f) ? 1.0f / d : 0.0f;
  const int swz = ((row >> 2) & 3) << 3;
  u16* la = As + row * 32 + ((q * 8) ^ swz);
  char* lB = (char*)Bs + ((t >> 6) << 10);
  const int goff = t << 4;
  for (int ks = 0; ks < 4; ++ks) {
    __syncthreads();
    const char* gB = (const char*)(K1T + ((size_t)ks * 256 + n0) * 32);
    gl_lds16(gB + goff, lB);
    gl_lds16(gB + 4096 + goff, lB + 4096);
    f32x4 s0 = fz, s1 = fz;
    const u16* p = src + ks * 32;
#pragma unroll
    for (int sp = 0; sp < 8; ++sp) {
      H8 L;
      L.u = *(const uint4*)(p + (size_t)sp * N8K * 128);
#pragma unroll
      for (int jj = 0; jj < 4; ++jj) {
        s0[jj] += (float)L.h[jj];
        s1[jj] += (float)L.h[4 + jj];
      }
    }
    s0 *= inv; s1 *= inv;
    uint4 w;
    w.x = pkf(s0[0], s0[1]); w.y = pkf(s0[2], s0[3]);
    w.z = pkf(s1[0], s1[1]); w.w = pkf(s1[2], s1[3]);
    *(uint4*)la = w;
    __syncthreads();
    short8 afr[4], bfr[2];
#pragma unroll
    for (int i = 0; i < 4; ++i) afr[i] = *(const short8*)(As + aoff[i]);
#pragma unroll
    for (int j = 0; j < 2; ++j) bfr[j] = *(const short8*)(Bs + boff[j]);
#pragma unroll
    for (int i = 0; i < 4; ++i)
#pragma unroll
      for (int j = 0; j < 2; ++j)
        acc[i][j] = __builtin_amdgcn_mfma_f32_16x16x32_bf16(afr[i], bfr[j], acc[i][j], 0, 0, 0);
  }
#pragma unroll
  for (int j = 0; j < 2; ++j) {
    int c = n0 + wn + j * 16 + fm;
    float bc = bias[c];
    float t1 = 0.f, t2 = 0.f;
#pragma unroll
    for (int i = 0; i < 4; ++i) {
      int r = m0 + i * 16 + fq * 4;
#pragma unroll
      for (int ii = 0; ii < 4; ++ii) {
        float v = acc[i][j][ii] + bc;
        region1b[(size_t)(r + ii) * 256 + c] = f2b(v);
        t1 += v; t2 += v * v;
      }
    }
    t1 += __shfl_xor(t1, 16); t1 += __shfl_xor(t1, 32);
    t2 += __shfl_xor(t2, 16); t2 += __shfl_xor(t2, 32);
    if (fq == 0) { atomicAdd(&bns[c], t1); atomicAdd(&bnq[c], t2); }
  }
}

// ---------------------------------------------------------------------------
// BNH (BM=32): H = (BN1(region1b)*invdeg) @ K2. grid 256 (1 block/CU).
// region1b is bf16. Writes HT[r/32][128][r&31] bf16.
// ---------------------------------------------------------------------------
__global__ __launch_bounds__(256, 2)
void k_bnH(const u16* __restrict__ region1b, const float* __restrict__ deg,
           const float* __restrict__ bn1s, const float* __restrict__ bn1q,
           const float* __restrict__ g1, const float* __restrict__ be1,
           const u16* __restrict__ K2T, u16* __restrict__ HT) {
  __shared__ __align__(16) u16 As[32 * 32];
  __shared__ __align__(16) u16 Bs[128 * 32];
  __shared__ float scS[256], shS[256];
  const int t = threadIdx.x, mt = blockIdx.x;
  const int m0 = mt << 5;
  const int lane = t & 63, wv = t >> 6;
  const int wn = wv << 5;
  const int fm = lane & 15, fq = lane >> 4;
  {
    float mu = bn1s[t] * (1.0f / 8192.0f);
    float var = bn1q[t] * (1.0f / 8192.0f) - mu * mu;
    float iv = rsqrtf(var + 1e-3f);
    float sc = iv * g1[t];
    scS[t] = sc;
    shS[t] = be1[t] - mu * sc;
  }
  const f32x4 fz = {0.f, 0.f, 0.f, 0.f};
  f32x4 acc[2][2];
#pragma unroll
  for (int i = 0; i < 2; ++i)
#pragma unroll
    for (int j = 0; j < 2; ++j) acc[i][j] = fz;
  int aoff[2], boff[2];
#pragma unroll
  for (int i = 0; i < 2; ++i) {
    int m = i * 16 + fm;
    aoff[i] = m * 32 + ((fq * 8) ^ (((m >> 2) & 3) << 3));
  }
#pragma unroll
  for (int j = 0; j < 2; ++j) boff[j] = (wn + j * 16 + fm) * 32 + fq * 8;
  const int row = t >> 3, oct = t & 7;
  float d = deg[m0 + row];
  const float idg = (d > 0.5f) ? 1.0f / d : 0.0f;
  const u16* src = region1b + (size_t)(m0 + row) * 256 + oct * 4;
  const int swz = ((row >> 2) & 3) << 3;
  u16* la = As + row * 32 + ((oct * 4) ^ swz);
  char* lB = (char*)Bs + ((t >> 6) << 10);
  const int goff = t << 4;
  for (int ks = 0; ks < 8; ++ks) {
    __syncthreads();
    const char* gB = (const char*)(K2T + (size_t)ks * 4096);
    gl_lds16(gB + goff, lB);
    gl_lds16(gB + 4096 + goff, lB + 4096);
    const int cb = ks * 32 + oct * 4;
    uint2 xw = *(const uint2*)(src + ks * 32);
    float x0 = b2f((u16)(xw.x & 0xFFFFu)), x1 = b2f((u16)(xw.x >> 16));
    float x2 = b2f((u16)(xw.y & 0xFFFFu)), x3 = b2f((u16)(xw.y >> 16));
    float y0 = (x0 * scS[cb + 0] + shS[cb + 0]) * idg;
    float y1 = (x1 * scS[cb + 1] + shS[cb + 1]) * idg;
    float y2 = (x2 * scS[cb + 2] + shS[cb + 2]) * idg;
    float y3 = (x3 * scS[cb + 3] + shS[cb + 3]) * idg;
    uint2 w;
    w.x = pkf(y0, y1);
    w.y = pkf(y2, y3);
    *(uint2*)la = w;
    __syncthreads();
    short8 afr[2], bfr[2];
#pragma unroll
    for (int i = 0; i < 2; ++i) afr[i] = *(const short8*)(As + aoff[i]);
#pragma unroll
    for (int j = 0; j < 2; ++j) bfr[j] = *(const short8*)(Bs + boff[j]);
#pragma unroll
    for (int i = 0; i < 2; ++i)
#pragma unroll
      for (int j = 0; j < 2; ++j)
        acc[i][j] = __builtin_amdgcn_mfma_f32_16x16x32_bf16(afr[i], bfr[j], acc[i][j], 0, 0, 0);
  }
#pragma unroll
  for (int i = 0; i < 2; ++i)
#pragma unroll
    for (int j = 0; j < 2; ++j) {
      int c = wn + j * 16 + fm;
      int r = m0 + i * 16 + fq * 4;
      uint2 w;
      w.x = pkf(acc[i][j][0], acc[i][j][1]);
      w.y = pkf(acc[i][j][2], acc[i][j][3]);
      *(uint2*)(HT + (size_t)(r >> 5) * 4096 + c * 32 + (r & 31)) = w;
    }
}

// ---------------------------------------------------------------------------
// GEMM2 (BK=128, R10 version — no register prefetch): C[m=p][n=c] =
// sum_r adj[p][r]*H[r][c]. grid 64 mt x 8 splits. A from RB rowbits (uint4 +
// unpack16 -> swizzled LDS); B(HT) via 8x global_load_lds.
// Out P2h[s][p][128 c] fp16.
// ---------------------------------------------------------------------------
__global__ __launch_bounds__(256, 2)
void k_gemm2(const u32* __restrict__ RB, const u16* __restrict__ HT,
             u16* __restrict__ P2h) {
  __shared__ __align__(16) u16 As[4 * 128 * 32];
  __shared__ __align__(16) u16 Bs[4 * 128 * 32];
  const int t = threadIdx.x, bx = blockIdx.x;
  const int mt = bx & 63, s = bx >> 6;
  const int m0 = mt << 7;
  const int lane = t & 63, wv = t >> 6;
  const int wm = (wv & 1) << 6, wn = (wv >> 1) << 6;
  const int fm = lane & 15, fq = lane >> 4;
  ZERO_ACC();
  int aoff[4], boff[4];
#pragma unroll
  for (int i = 0; i < 4; ++i) {
    int m = wm + i * 16 + fm;
    aoff[i] = m * 32 + ((fq * 8) ^ (((m >> 2) & 3) << 3));
  }
#pragma unroll
  for (int j = 0; j < 4; ++j) boff[j] = (wn + j * 16 + fm) * 32 + fq * 8;
  const int row = t >> 1, h = t & 1;
  const u32* gA = RB + (size_t)(m0 + row) * 256 + s * 32;
  const char* gB = (const char*)(HT + (size_t)s * 32 * 4096);
  char* lB = (char*)Bs + ((t >> 6) << 10);
  const int goff = t << 4;
  const int swzA = ((row >> 2) & 3) << 3;
  u16* la0 = As + row * 32 + ((h * 16) ^ swzA);
  u16* la1 = As + row * 32 + (((h * 16) + 8) ^ swzA);
  for (int ks = 0; ks < 8; ++ks) {
    __syncthreads();
#pragma unroll
    for (int ph = 0; ph < 8; ++ph) gl_lds16(gB + ph * 4096 + goff, lB + ph * 4096);
    uint4 w4 = *(const uint4*)(gA + ks * 4);
    gB += 32768;
    u32 ws[4] = {w4.x, w4.y, w4.z, w4.w};
#pragma unroll
    for (int ph = 0; ph < 4; ++ph) {
      u32 bits = (ws[ph] >> (h * 16)) & 0xFFFFu;
      uint4 o0, o1;
      unpack16(bits, o0, o1);
      *(uint4*)(la0 + ph * 4096) = o0;
      *(uint4*)(la1 + ph * 4096) = o1;
    }
    __syncthreads();
#pragma unroll
    for (int ph = 0; ph < 4; ++ph)
      MFMA_4x4((As + ph * 4096), (Bs + ph * 4096), aoff, boff);
  }
  u16* base = P2h + (size_t)s * N8K * 128;
#pragma unroll
  for (int i = 0; i < 4; ++i)
#pragma unroll
    for (int j = 0; j < 4; ++j) {
      int c = wn + j * 16 + fm;
      int pr = m0 + wm + i * 16 + fq * 4;
#pragma unroll
      for (int ii = 0; ii < 4; ++ii)
        base[(size_t)(pr + ii) * 128 + c] = f2h(acc[i][j][ii]);
    }
}

// ---------------------------------------------------------------------------
// RED2: people1 = sum_s P2h + b2, fused BN2 sum/sumsq stats. Paired-column
// u32 fp16 loads; float2 stores.
// ---------------------------------------------------------------------------
__global__ void k_red2(const u16* __restrict__ P2h, const float* __restrict__ bias,
                       float* __restrict__ people1,
                       float* __restrict__ bn2s, float* __restrict__ bn2q) {
  __shared__ float r1[512], r2[512];
  const int t = threadIdx.x;
  const int c = (t & 63) * 2, pg = t >> 6;
  const int p0 = blockIdx.x << 5;
  const float bc0 = bias[c], bc1 = bias[c + 1];
  float s1a = 0.f, s2a = 0.f, s1b = 0.f, s2b = 0.f;
  for (int pp = pg; pp < 32; pp += 4) {
    size_t o = (size_t)(p0 + pp) * 128 + c;
    float v0 = bc0, v1 = bc1;
#pragma unroll
    for (int s = 0; s < 8; ++s) {
      H2 L;
      L.u = *(const u32*)(P2h + (size_t)s * N8K * 128 + o);
      v0 += (float)L.h[0];
      v1 += (float)L.h[1];
    }
    float2 st; st.x = v0; st.y = v1;
    *(float2*)(people1 + o) = st;
    s1a += v0; s2a += v0 * v0;
    s1b += v1; s2b += v1 * v1;
  }
  r1[t * 2] = s1a; r1[t * 2 + 1] = s1b;
  r2[t * 2] = s2a; r2[t * 2 + 1] = s2b;
  __syncthreads();
  if (t < 128) {
    float a = 0.f, b = 0.f;
#pragma unroll
    for (int g = 0; g < 4; ++g) {
      int idx = ((t >> 1) + 64 * g) * 2 + (t & 1);
      a += r1[idx]; b += r2[idx];
    }
    atomicAdd(&bn2s[t], a);
    atomicAdd(&bn2q[t], b);
  }
}

// ---------------------------------------------------------------------------
// BN2APPLY: out = BN2(people1); output dtype via per-block vote on feat.
// ---------------------------------------------------------------------------
__global__ void k_bn2apply(const float* __restrict__ people1,
                           const float* __restrict__ bn2s, const float* __restrict__ bn2q,
                           const float* __restrict__ g2, const float* __restrict__ be2,
                           const u16* __restrict__ featprobe, void* __restrict__ outv) {
  const int flag = dvote(featprobe);
  int g = blockIdx.x * 256 + threadIdx.x;
  int p = g >> 5;
  int c = (g & 31) << 2;
  f32x4 x = *(const f32x4*)(people1 + (size_t)p * 128 + c);
  f32x4 y;
#pragma unroll
  for (int jj = 0; jj < 4; ++jj) {
    int cc = c + jj;
    float mu = bn2s[cc] * (1.0f / 8192.0f);
    float var = bn2q[cc] * (1.0f / 8192.0f) - mu * mu;
    float inv = rsqrtf(var + 1e-3f);
    y[jj] = (x[jj] - mu) * inv * g2[cc] + be2[cc];
  }
  if (flag) {
    uint2 w;
    w.x = pkf(y[0], y[1]);
    w.y = pkf(y[2], y[3]);
    *(uint2*)((u16*)outv + (size_t)p * 128 + c) = w;
  } else {
    *(f32x4*)((float*)outv + (size_t)p * 128 + c) = y;
  }
}

// ---------------------------------------------------------------------------
// Workspace (~56.3 MB):
//  [0,16M)   Ph: P1h (8 x 2MB fp16) then P2h (8 x 2MB fp16)
//  [32M,36M) region1b bf16   [40M,44M) people1 fp32
//  [44M,46M) Ft bf16         [46M,48M) HT bf16
//  [48M,56M) RB rowbits u32 (written by gemm1, read by gemm2)
//  [56M,..)  K1T(64K), K2T(64K), deg(32K), par, bn stats
// ---------------------------------------------------------------------------
extern "C" void kernel_launch(void* const* d_in, const int* in_sizes, int n_in,
                              void* d_out, int out_size, void* d_ws, size_t ws_size,
                              hipStream_t stream) {
  const void* feat = d_in[0];
  const int* adj   = (const int*)d_in[1];
  const void* K1   = d_in[2];
  const void* b1   = d_in[3];
  const void* g1   = d_in[4];
  const void* be1  = d_in[5];
  const void* K2   = d_in[6];
  const void* b2   = d_in[7];
  const void* g2   = d_in[8];
  const void* be2  = d_in[9];
  char* ws = (char*)d_ws;
  const size_t MB = 1u << 20;

  u16*   Ph       = (u16*)(ws);
  u16*   region1b = (u16*)(ws + 32 * MB);
  float* people1  = (float*)(ws + 40 * MB);
  u16*   Ft       = (u16*)(ws + 44 * MB);
  u16*   HT       = (u16*)(ws + 46 * MB);
  u32*   RB       = (u32*)(ws + 48 * MB);
  u16*   K1T      = (u16*)(ws + 56 * MB);
  u16*   K2T      = K1T + 32768;
  float* deg      = (float*)(K2T + 32768);
  float* par      = deg + N8K;
  float* bn1s     = par + 1152;
  float* bn1q     = bn1s + 256;
  float* bn2s     = bn1q + 256;
  float* bn2q     = bn2s + 128;

  k_prep<<<289, 256, 0, stream>>>(feat, K1, K2, b1, g1, be1, b2, g2, be2,
                                  Ft, K1T, K2T, deg, par, bn1s, bn1q, bn2s, bn2q);
  k_gemm1<<<512, 256, 0, stream>>>(adj, Ft, Ph, deg, RB);
  k_projf<<<256, 256, 0, stream>>>(Ph, deg, K1T, par + 0, region1b, bn1s, bn1q);
  k_bnH<<<256, 256, 0, stream>>>(region1b, deg, bn1s, bn1q, par + 256, par + 512,
                                 K2T, HT);
  k_gemm2<<<512, 256, 0, stream>>>(RB, HT, Ph);
  k_red2<<<256, 256, 0, stream>>>(Ph, par + 768, people1, bn2s, bn2q);
  k_bn2apply<<<1024, 256, 0, stream>>>(people1, bn2s, bn2q, par + 896, par + 1024,
                                       (const u16*)feat, d_out);
}

// Round 13
// 437.390 us; speedup vs baseline: 1.0334x; 1.0252x over previous
//
#include <hip/hip_runtime.h>
#include <stdint.h>

typedef unsigned int u32;
typedef unsigned short u16;
typedef unsigned long long u64;
typedef __attribute__((ext_vector_type(8))) short short8;
typedef __attribute__((ext_vector_type(4))) float f32x4;

#define N8K 8192

__device__ __forceinline__ float b2f(u16 u) { return __uint_as_float(((u32)u) << 16); }
__device__ __forceinline__ u16 f2b(float f) {
  u32 i = __float_as_uint(f);
  i += 0x7FFFu + ((i >> 16) & 1u);
  return (u16)(i >> 16);
}
// fp16 (RNE) helpers for split-K partials
__device__ __forceinline__ u16 f2h(float f) {
  union { _Float16 h; u16 u; } x; x.h = (_Float16)f; return x.u;
}
__device__ __forceinline__ u32 pkh(float a, float b) {
  return (u32)f2h(a) | ((u32)f2h(b) << 16);
}
union H8 { uint4 u; _Float16 h[8]; };
union H4 { uint2 u; _Float16 h[4]; };
union H2 { u32 u; _Float16 h[2]; };
// pack two 0/1 ints into two bf16 halves
__device__ __forceinline__ u32 pk01(int x, int y) { return (u32)__mul24(x | (y << 16), 0x3F80); }
__device__ __forceinline__ u32 pkf(float a, float b) { return (u32)f2b(a) | ((u32)f2b(b) << 16); }

// block-uniform dtype vote: 1 = tensors are bf16, 0 = fp32
__device__ __forceinline__ int dvote(const u16* f16) {
  u16 u = f16[threadIdx.x * 2];
  int e = (u >> 7) & 0xFF;
  return __syncthreads_count((e >= 0x60 && e <= 0x9F) ? 1 : 0) >= 128;
}

// async global->LDS, 16B/lane; lds dest wave-uniform base (+lane*16)
__device__ __forceinline__ void gl_lds16(const void* g, void* l) {
  __builtin_amdgcn_global_load_lds(
      (const __attribute__((address_space(1))) u32*)g,
      (__attribute__((address_space(3))) u32*)l, 16, 0, 0);
}

// 16 bits (0/1 adjacency) -> 8 u32 bf16-pairs (1.0f bf16 = 0x3F80)
__device__ __forceinline__ void unpack16(u32 b, uint4& o0, uint4& o1) {
  o0.x = ((b & 0x0001u) ? 0x3F80u : 0u) | ((b & 0x0002u) ? 0x3F800000u : 0u);
  o0.y = ((b & 0x0004u) ? 0x3F80u : 0u) | ((b & 0x0008u) ? 0x3F800000u : 0u);
  o0.z = ((b & 0x0010u) ? 0x3F80u : 0u) | ((b & 0x0020u) ? 0x3F800000u : 0u);
  o0.w = ((b & 0x0040u) ? 0x3F80u : 0u) | ((b & 0x0080u) ? 0x3F800000u : 0u);
  o1.x = ((b & 0x0100u) ? 0x3F80u : 0u) | ((b & 0x0200u) ? 0x3F800000u : 0u);
  o1.y = ((b & 0x0400u) ? 0x3F80u : 0u) | ((b & 0x0800u) ? 0x3F800000u : 0u);
  o1.z = ((b & 0x1000u) ? 0x3F80u : 0u) | ((b & 0x2000u) ? 0x3F800000u : 0u);
  o1.w = ((b & 0x4000u) ? 0x3F80u : 0u) | ((b & 0x8000u) ? 0x3F800000u : 0u);
}

// 4 waves, each a 64x64 quadrant; 4x4 subtiles of 16x16x32 bf16 MFMA.
#define MFMA_4x4(As_, Bs_, aoff_, boff_)                                         \
  {                                                                              \
    short8 afr[4], bfr[4];                                                       \
    _Pragma("unroll") for (int i_ = 0; i_ < 4; ++i_)                             \
      afr[i_] = *(const short8*)(As_ + aoff_[i_]);                               \
    _Pragma("unroll") for (int j_ = 0; j_ < 4; ++j_)                             \
      bfr[j_] = *(const short8*)(Bs_ + boff_[j_]);                               \
    _Pragma("unroll") for (int i_ = 0; i_ < 4; ++i_)                             \
      _Pragma("unroll") for (int j_ = 0; j_ < 4; ++j_)                           \
        acc[i_][j_] = __builtin_amdgcn_mfma_f32_16x16x32_bf16(                   \
            afr[i_], bfr[j_], acc[i_][j_], 0, 0, 0);                             \
  }

#define ZERO_ACC()                                                               \
  f32x4 acc[4][4];                                                               \
  {                                                                              \
    const f32x4 fz = {0.f, 0.f, 0.f, 0.f};                                       \
    _Pragma("unroll") for (int i_ = 0; i_ < 4; ++i_)                             \
      _Pragma("unroll") for (int j_ = 0; j_ < 4; ++j_) acc[i_][j_] = fz;         \
  }

// ---------------------------------------------------------------------------
// PREP: Ft via coalesced LDS-tile transpose; K1T/K2T gathers; params->fp32;
// zero deg + BN stats. (289 blocks, no adj access.)
// Ft:  [256 k0][128 f][32 p]  K1T: [4 k0][256 c][32 f]  K2T: [8 k0][128 c][32 f]
// ---------------------------------------------------------------------------
__global__ void k_prep(const void* __restrict__ featv, const void* __restrict__ K1v,
                       const void* __restrict__ K2v,
                       const void* __restrict__ b1v, const void* __restrict__ g1v,
                       const void* __restrict__ be1v, const void* __restrict__ b2v,
                       const void* __restrict__ g2v, const void* __restrict__ be2v,
                       u16* __restrict__ Ft, u16* __restrict__ K1T, u16* __restrict__ K2T,
                       float* __restrict__ deg, float* __restrict__ par,
                       float* __restrict__ bn1s, float* __restrict__ bn1q,
                       float* __restrict__ bn2s, float* __restrict__ bn2q) {
  const int b = blockIdx.x, t = threadIdx.x;
  const int flag = dvote((const u16*)featv);
  if (b < 256) {
    __shared__ __align__(16) u16 Lf[32 * 136];
    const int pr = t >> 3, ck = t & 7;
    u16 v[16];
    if (flag) {
      const u16* s = (const u16*)featv + (size_t)(b * 32 + pr) * 128 + ck * 16;
      *(uint4*)&v[0] = *(const uint4*)(s);
      *(uint4*)&v[8] = *(const uint4*)(s + 8);
    } else {
      const float* s = (const float*)featv + (size_t)(b * 32 + pr) * 128 + ck * 16;
#pragma unroll
      for (int i = 0; i < 16; ++i) v[i] = f2b(s[i]);
    }
    *(uint4*)(Lf + pr * 136 + ck * 16) = *(uint4*)&v[0];
    *(uint4*)(Lf + pr * 136 + ck * 16 + 8) = *(uint4*)&v[8];
    __syncthreads();
    const int f = t >> 1, h16 = (t & 1) * 16;
    u32 w[8];
#pragma unroll
    for (int i = 0; i < 8; ++i) {
      u16 lo = Lf[(h16 + 2 * i) * 136 + f];
      u16 hi = Lf[(h16 + 2 * i + 1) * 136 + f];
      w[i] = (u32)lo | ((u32)hi << 16);
    }
    u16* d = Ft + (size_t)b * 4096 + f * 32 + h16;
    *(uint4*)(d) = *(uint4*)&w[0];
    *(uint4*)(d + 8) = *(uint4*)&w[4];
  } else if (b < 272) {
    int o = ((b - 256) * 256 + t) << 3;
    int k0 = o >> 13, c = (o >> 5) & 255, kk = o & 31;
    uint4 w;
    if (flag) {
      const u16* s = (const u16*)K1v + (size_t)(k0 * 32 + kk) * 256 + c;
      w.x = (u32)s[0]    | ((u32)s[256]  << 16);
      w.y = (u32)s[512]  | ((u32)s[768]  << 16);
      w.z = (u32)s[1024] | ((u32)s[1280] << 16);
      w.w = (u32)s[1536] | ((u32)s[1792] << 16);
    } else {
      const float* s = (const float*)K1v + (size_t)(k0 * 32 + kk) * 256 + c;
      w.x = pkf(s[0], s[256]); w.y = pkf(s[512], s[768]);
      w.z = pkf(s[1024], s[1280]); w.w = pkf(s[1536], s[1792]);
    }
    *(uint4*)(K1T + o) = w;
  } else if (b < 288) {
    int o = ((b - 272) * 256 + t) << 3;
    int k0 = o >> 12, c = (o >> 5) & 127, kk = o & 31;
    uint4 w;
    if (flag) {
      const u16* s = (const u16*)K2v + (size_t)(k0 * 32 + kk) * 128 + c;
      w.x = (u32)s[0]   | ((u32)s[128] << 16);
      w.y = (u32)s[256] | ((u32)s[384] << 16);
      w.z = (u32)s[512] | ((u32)s[640] << 16);
      w.w = (u32)s[768] | ((u32)s[896] << 16);
    } else {
      const float* s = (const float*)K2v + (size_t)(k0 * 32 + kk) * 128 + c;
      w.x = pkf(s[0], s[128]); w.y = pkf(s[256], s[384]);
      w.z = pkf(s[512], s[640]); w.w = pkf(s[768], s[896]);
    }
    *(uint4*)(K2T + o) = w;
  } else {
    if (t < 256) {
      par[t]       = flag ? b2f(((const u16*)b1v)[t])  : ((const float*)b1v)[t];
      par[256 + t] = flag ? b2f(((const u16*)g1v)[t])  : ((const float*)g1v)[t];
      par[512 + t] = flag ? b2f(((const u16*)be1v)[t]) : ((const float*)be1v)[t];
      bn1s[t] = 0.f; bn1q[t] = 0.f;
    }
    if (t < 128) {
      par[768 + t]  = flag ? b2f(((const u16*)b2v)[t])  : ((const float*)b2v)[t];
      par[896 + t]  = flag ? b2f(((const u16*)g2v)[t])  : ((const float*)g2v)[t];
      par[1024 + t] = flag ? b2f(((const u16*)be2v)[t]) : ((const float*)be2v)[t];
      bn2s[t] = 0.f; bn2q[t] = 0.f;
    }
    for (int i = t; i < N8K; i += 256) deg[i] = 0.f;
  }
}

// ---------------------------------------------------------------------------
// GEMM1 (BK=128): C[m=f][n=r] = sum_p Ft[f][p]*adj[p][r]. grid 64 nt x 8
// splits, 8 iters of 128-K. A(Ft) via 8x global_load_lds; B: 16x adj int4 ->
// pk01 -> swizzled LDS. deg free; RB rowbits emitted via shuffle-OR into the
// COALESCED layout RB2[wg=nt][p][4 words] (one block owns a contiguous
// [1024 p][16B] region -> full-line writes). Out P1h[s][r][128 f] fp16.
// ---------------------------------------------------------------------------
__global__ __launch_bounds__(256, 2)
void k_gemm1(const int* __restrict__ adj, const u16* __restrict__ Ft,
             u16* __restrict__ P1h, float* __restrict__ deg,
             u32* __restrict__ RB) {
  __shared__ __align__(16) u16 As[4 * 128 * 32];
  __shared__ __align__(16) u16 Bs[4 * 128 * 32];
  __shared__ float degp[128];
  const int t = threadIdx.x, bx = blockIdx.x;
  const int nt = bx & 63, s = bx >> 6;
  const int n0 = nt << 7;
  const int lane = t & 63, wv = t >> 6;
  const int wm = (wv & 1) << 6, wn = (wv >> 1) << 6;
  const int fm = lane & 15, fq = lane >> 4;
  if (t < 128) degp[t] = 0.0f;
  ZERO_ACC();
  int aoff[4], boff[4];
#pragma unroll
  for (int i = 0; i < 4; ++i) aoff[i] = (wm + i * 16 + fm) * 32 + fq * 8;
#pragma unroll
  for (int j = 0; j < 4; ++j) {
    int n = wn + j * 16 + fm;
    boff[j] = n * 32 + ((fq * 8) ^ (((n >> 2) & 3) << 3));
  }
  const int rb = t & 31, kb = t >> 5;
  const int* gB = adj + ((size_t)s * 1024 + kb * 4) * N8K + n0 + rb * 4;
  const char* gA = (const char*)(Ft + (size_t)s * 32 * 4096);
  char* lA = (char*)As + ((t >> 6) << 10);
  const int goff = t << 4;
  u16* lb0 = Bs + (rb * 4) * 32 + ((kb * 4) ^ ((rb & 3) << 3));
  const int sh4 = (rb & 7) * 4;
  // RB2[wg=nt][p][wi]: this thread's word column wi = rb>>3, rows s*1024+kb*4+...
  u32* dstN = RB + (size_t)nt * 32768 + (size_t)(s * 1024 + kb * 4) * 4 + (rb >> 3);
  int ds0 = 0, ds1 = 0, ds2 = 0, ds3 = 0;
  for (int ks = 0; ks < 8; ++ks) {
    __syncthreads();
#pragma unroll
    for (int ph = 0; ph < 8; ++ph) gl_lds16(gA + ph * 4096 + goff, lA + ph * 4096);
    gA += 32768;
#pragma unroll
    for (int ph = 0; ph < 4; ++ph) {
      const int* g = gB + (size_t)ph * 32 * N8K;
      int4 a0 = *(const int4*)(g);
      int4 a1 = *(const int4*)(g + N8K);
      int4 a2 = *(const int4*)(g + 2 * N8K);
      int4 a3 = *(const int4*)(g + 3 * N8K);
      ds0 += a0.x + a1.x + a2.x + a3.x;
      ds1 += a0.y + a1.y + a2.y + a3.y;
      ds2 += a0.z + a1.z + a2.z + a3.z;
      ds3 += a0.w + a1.w + a2.w + a3.w;
      u16* lb = lb0 + ph * 4096;
      uint2 w;
      w.x = pk01(a0.x, a1.x); w.y = pk01(a2.x, a3.x); *(uint2*)(lb) = w;
      w.x = pk01(a0.y, a1.y); w.y = pk01(a2.y, a3.y); *(uint2*)(lb + 32) = w;
      w.x = pk01(a0.z, a1.z); w.y = pk01(a2.z, a3.z); *(uint2*)(lb + 64) = w;
      w.x = pk01(a0.w, a1.w); w.y = pk01(a2.w, a3.w); *(uint2*)(lb + 96) = w;
      u32 v0 = ((u32)a0.x | ((u32)a0.y << 1) | ((u32)a0.z << 2) | ((u32)a0.w << 3)) << sh4;
      u32 v1 = ((u32)a1.x | ((u32)a1.y << 1) | ((u32)a1.z << 2) | ((u32)a1.w << 3)) << sh4;
      u32 v2 = ((u32)a2.x | ((u32)a2.y << 1) | ((u32)a2.z << 2) | ((u32)a2.w << 3)) << sh4;
      u32 v3 = ((u32)a3.x | ((u32)a3.y << 1) | ((u32)a3.z << 2) | ((u32)a3.w << 3)) << sh4;
      v0 |= __shfl_xor(v0, 1); v0 |= __shfl_xor(v0, 2); v0 |= __shfl_xor(v0, 4);
      v1 |= __shfl_xor(v1, 1); v1 |= __shfl_xor(v1, 2); v1 |= __shfl_xor(v1, 4);
      v2 |= __shfl_xor(v2, 1); v2 |= __shfl_xor(v2, 2); v2 |= __shfl_xor(v2, 4);
      v3 |= __shfl_xor(v3, 1); v3 |= __shfl_xor(v3, 2); v3 |= __shfl_xor(v3, 4);
      if ((rb & 7) == 0) {
        u32* d2 = dstN + (size_t)(ks * 128 + ph * 32) * 4;
        d2[0] = v0; d2[4] = v1; d2[8] = v2; d2[12] = v3;
      }
    }
    gB += 128 * N8K;
    __syncthreads();
#pragma unroll
    for (int ph = 0; ph < 4; ++ph)
      MFMA_4x4((As + ph * 4096), (Bs + ph * 4096), aoff, boff);
  }
  atomicAdd(&degp[rb * 4 + 0], (float)ds0);
  atomicAdd(&degp[rb * 4 + 1], (float)ds1);
  atomicAdd(&degp[rb * 4 + 2], (float)ds2);
  atomicAdd(&degp[rb * 4 + 3], (float)ds3);
  u16* base = P1h + ((size_t)s * N8K + n0) * 128;
#pragma unroll
  for (int i = 0; i < 4; ++i)
#pragma unroll
    for (int j = 0; j < 4; ++j) {
      int r = wn + j * 16 + fm;
      int f = wm + i * 16 + fq * 4;
      uint2 w;
      w.x = pkh(acc[i][j][0], acc[i][j][1]);
      w.y = pkh(acc[i][j][2], acc[i][j][3]);
      *(uint2*)(base + (size_t)r * 128 + f) = w;
    }
  __syncthreads();
  if (t < 128) atomicAdd(&deg[n0 + t], degp[t]);
}

// ---------------------------------------------------------------------------
// PROJF1 (BM=64): region1b = bf16( (sum_s P1h * invdeg) @ K1 + b1 ), fused BN1
// stats. grid 256 = 128 mt x 2 ct.
// ---------------------------------------------------------------------------
__global__ __launch_bounds__(256, 2)
void k_projf(const u16* __restrict__ P1h, const float* __restrict__ deg,
             const u16* __restrict__ K1T, const float* __restrict__ bias,
             u16* __restrict__ region1b, float* __restrict__ bns, float* __restrict__ bnq) {
  __shared__ __align__(16) u16 As[64 * 32];
  __shared__ __align__(16) u16 Bs[128 * 32];
  const int t = threadIdx.x, bx = blockIdx.x;
  const int ct = bx & 1, mt = bx >> 1;
  const int m0 = mt << 6, n0 = ct << 7;
  const int lane = t & 63, wv = t >> 6;
  const int wn = wv << 5;
  const int fm = lane & 15, fq = lane >> 4;
  const f32x4 fz = {0.f, 0.f, 0.f, 0.f};
  f32x4 acc[4][2];
#pragma unroll
  for (int i = 0; i < 4; ++i)
#pragma unroll
    for (int j = 0; j < 2; ++j) acc[i][j] = fz;
  int aoff[4], boff[2];
#pragma unroll
  for (int i = 0; i < 4; ++i) {
    int m = i * 16 + fm;
    aoff[i] = m * 32 + ((fq * 8) ^ (((m >> 2) & 3) << 3));
  }
#pragma unroll
  for (int j = 0; j < 2; ++j) boff[j] = (wn + j * 16 + fm) * 32 + fq * 8;
  const int row = t >> 2, q = t & 3;
  const u16* src = P1h + (size_t)(m0 + row) * 128 + q * 8;
  float d = deg[m0 + row];
  const float inv = (d > 0.5f) ? 1.0f / d : 0.0f;
  const int swz = ((row >> 2) & 3) << 3;
  u16* la = As + row * 32 + ((q * 8) ^ swz);
  char* lB = (char*)Bs + ((t >> 6) << 10);
  const int goff = t << 4;
  for (int ks = 0; ks < 4; ++ks) {
    __syncthreads();
    const char* gB = (const char*)(K1T + ((size_t)ks * 256 + n0) * 32);
    gl_lds16(gB + goff, lB);
    gl_lds16(gB + 4096 + goff, lB + 4096);
    f32x4 s0 = fz, s1 = fz;
    const u16* p = src + ks * 32;
#pragma unroll
    for (int sp = 0; sp < 8; ++sp) {
      H8 L;
      L.u = *(const uint4*)(p + (size_t)sp * N8K * 128);
#pragma unroll
      for (int jj = 0; jj < 4; ++jj) {
        s0[jj] += (float)L.h[jj];
        s1[jj] += (float)L.h[4 + jj];
      }
    }
    s0 *= inv; s1 *= inv;
    uint4 w;
    w.x = pkf(s0[0], s0[1]); w.y = pkf(s0[2], s0[3]);
    w.z = pkf(s1[0], s1[1]); w.w = pkf(s1[2], s1[3]);
    *(uint4*)la = w;
    __syncthreads();
    short8 afr[4], bfr[2];
#pragma unroll
    for (int i = 0; i < 4; ++i) afr[i] = *(const short8*)(As + aoff[i]);
#pragma unroll
    for (int j = 0; j < 2; ++j) bfr[j] = *(const short8*)(Bs + boff[j]);
#pragma unroll
    for (int i = 0; i < 4; ++i)
#pragma unroll
      for (int j = 0; j < 2; ++j)
        acc[i][j] = __builtin_amdgcn_mfma_f32_16x16x32_bf16(afr[i], bfr[j], acc[i][j], 0, 0, 0);
  }
#pragma unroll
  for (int j = 0; j < 2; ++j) {
    int c = n0 + wn + j * 16 + fm;
    float bc = bias[c];
    float t1 = 0.f, t2 = 0.f;
#pragma unroll
    for (int i = 0; i < 4; ++i) {
      int r = m0 + i * 16 + fq * 4;
#pragma unroll
      for (int ii = 0; ii < 4; ++ii) {
        float v = acc[i][j][ii] + bc;
        region1b[(size_t)(r + ii) * 256 + c] = f2b(v);
        t1 += v; t2 += v * v;
      }
    }
    t1 += __shfl_xor(t1, 16); t1 += __shfl_xor(t1, 32);
    t2 += __shfl_xor(t2, 16); t2 += __shfl_xor(t2, 32);
    if (fq == 0) { atomicAdd(&bns[c], t1); atomicAdd(&bnq[c], t2); }
  }
}

// ---------------------------------------------------------------------------
// BNH (BM=32): H = (BN1(region1b)*invdeg) @ K2. grid 256 (1 block/CU).
// region1b is bf16. Writes HT[r/32][128][r&31] bf16.
// ---------------------------------------------------------------------------
__global__ __launch_bounds__(256, 2)
void k_bnH(const u16* __restrict__ region1b, const float* __restrict__ deg,
           const float* __restrict__ bn1s, const float* __restrict__ bn1q,
           const float* __restrict__ g1, const float* __restrict__ be1,
           const u16* __restrict__ K2T, u16* __restrict__ HT) {
  __shared__ __align__(16) u16 As[32 * 32];
  __shared__ __align__(16) u16 Bs[128 * 32];
  __shared__ float scS[256], shS[256];
  const int t = threadIdx.x, mt = blockIdx.x;
  const int m0 = mt << 5;
  const int lane = t & 63, wv = t >> 6;
  const int wn = wv << 5;
  const int fm = lane & 15, fq = lane >> 4;
  {
    float mu = bn1s[t] * (1.0f / 8192.0f);
    float var = bn1q[t] * (1.0f / 8192.0f) - mu * mu;
    float iv = rsqrtf(var + 1e-3f);
    float sc = iv * g1[t];
    scS[t] = sc;
    shS[t] = be1[t] - mu * sc;
  }
  const f32x4 fz = {0.f, 0.f, 0.f, 0.f};
  f32x4 acc[2][2];
#pragma unroll
  for (int i = 0; i < 2; ++i)
#pragma unroll
    for (int j = 0; j < 2; ++j) acc[i][j] = fz;
  int aoff[2], boff[2];
#pragma unroll
  for (int i = 0; i < 2; ++i) {
    int m = i * 16 + fm;
    aoff[i] = m * 32 + ((fq * 8) ^ (((m >> 2) & 3) << 3));
  }
#pragma unroll
  for (int j = 0; j < 2; ++j) boff[j] = (wn + j * 16 + fm) * 32 + fq * 8;
  const int row = t >> 3, oct = t & 7;
  float d = deg[m0 + row];
  const float idg = (d > 0.5f) ? 1.0f / d : 0.0f;
  const u16* src = region1b + (size_t)(m0 + row) * 256 + oct * 4;
  const int swz = ((row >> 2) & 3) << 3;
  u16* la = As + row * 32 + ((oct * 4) ^ swz);
  char* lB = (char*)Bs + ((t >> 6) << 10);
  const int goff = t << 4;
  for (int ks = 0; ks < 8; ++ks) {
    __syncthreads();
    const char* gB = (const char*)(K2T + (size_t)ks * 4096);
    gl_lds16(gB + goff, lB);
    gl_lds16(gB + 4096 + goff, lB + 4096);
    const int cb = ks * 32 + oct * 4;
    uint2 xw = *(const uint2*)(src + ks * 32);
    float x0 = b2f((u16)(xw.x & 0xFFFFu)), x1 = b2f((u16)(xw.x >> 16));
    float x2 = b2f((u16)(xw.y & 0xFFFFu)), x3 = b2f((u16)(xw.y >> 16));
    float y0 = (x0 * scS[cb + 0] + shS[cb + 0]) * idg;
    float y1 = (x1 * scS[cb + 1] + shS[cb + 1]) * idg;
    float y2 = (x2 * scS[cb + 2] + shS[cb + 2]) * idg;
    float y3 = (x3 * scS[cb + 3] + shS[cb + 3]) * idg;
    uint2 w;
    w.x = pkf(y0, y1);
    w.y = pkf(y2, y3);
    *(uint2*)la = w;
    __syncthreads();
    short8 afr[2], bfr[2];
#pragma unroll
    for (int i = 0; i < 2; ++i) afr[i] = *(const short8*)(As + aoff[i]);
#pragma unroll
    for (int j = 0; j < 2; ++j) bfr[j] = *(const short8*)(Bs + boff[j]);
#pragma unroll
    for (int i = 0; i < 2; ++i)
#pragma unroll
      for (int j = 0; j < 2; ++j)
        acc[i][j] = __builtin_amdgcn_mfma_f32_16x16x32_bf16(afr[i], bfr[j], acc[i][j], 0, 0, 0);
  }
#pragma unroll
  for (int i = 0; i < 2; ++i)
#pragma unroll
    for (int j = 0; j < 2; ++j) {
      int c = wn + j * 16 + fm;
      int r = m0 + i * 16 + fq * 4;
      uint2 w;
      w.x = pkf(acc[i][j][0], acc[i][j][1]);
      w.y = pkf(acc[i][j][2], acc[i][j][3]);
      *(uint2*)(HT + (size_t)(r >> 5) * 4096 + c * 32 + (r & 31)) = w;
    }
}

// ---------------------------------------------------------------------------
// GEMM2 (BK=128): C[m=p][n=c] = sum_r adj[p][r]*H[r][c]. grid 64 mt x 8
// splits. A from RB2 rowbits (dense uint4 at (s*8+ks)*32768 + p*4 ->
// unpack16 -> swizzled LDS); B(HT) via 8x global_load_lds.
// Out P2h[s][p][128 c] fp16.
// ---------------------------------------------------------------------------
__global__ __launch_bounds__(256, 2)
void k_gemm2(const u32* __restrict__ RB, const u16* __restrict__ HT,
             u16* __restrict__ P2h) {
  __shared__ __align__(16) u16 As[4 * 128 * 32];
  __shared__ __align__(16) u16 Bs[4 * 128 * 32];
  const int t = threadIdx.x, bx = blockIdx.x;
  const int mt = bx & 63, s = bx >> 6;
  const int m0 = mt << 7;
  const int lane = t & 63, wv = t >> 6;
  const int wm = (wv & 1) << 6, wn = (wv >> 1) << 6;
  const int fm = lane & 15, fq = lane >> 4;
  ZERO_ACC();
  int aoff[4], boff[4];
#pragma unroll
  for (int i = 0; i < 4; ++i) {
    int m = wm + i * 16 + fm;
    aoff[i] = m * 32 + ((fq * 8) ^ (((m >> 2) & 3) << 3));
  }
#pragma unroll
  for (int j = 0; j < 4; ++j) boff[j] = (wn + j * 16 + fm) * 32 + fq * 8;
  const int row = t >> 1, h = t & 1;
  // RB2[wg][p][4]: wg = s*8+ks, this thread's row p = m0+row
  const u32* gA = RB + (size_t)(s * 8) * 32768 + (size_t)(m0 + row) * 4;
  const char* gB = (const char*)(HT + (size_t)s * 32 * 4096);
  char* lB = (char*)Bs + ((t >> 6) << 10);
  const int goff = t << 4;
  const int swzA = ((row >> 2) & 3) << 3;
  u16* la0 = As + row * 32 + ((h * 16) ^ swzA);
  u16* la1 = As + row * 32 + (((h * 16) + 8) ^ swzA);
  for (int ks = 0; ks < 8; ++ks) {
    __syncthreads();
#pragma unroll
    for (int ph = 0; ph < 8; ++ph) gl_lds16(gB + ph * 4096 + goff, lB + ph * 4096);
    uint4 w4 = *(const uint4*)(gA + (size_t)ks * 32768);
    gB += 32768;
    u32 ws[4] = {w4.x, w4.y, w4.z, w4.w};
#pragma unroll
    for (int ph = 0; ph < 4; ++ph) {
      u32 bits = (ws[ph] >> (h * 16)) & 0xFFFFu;
      uint4 o0, o1;
      unpack16(bits, o0, o1);
      *(uint4*)(la0 + ph * 4096) = o0;
      *(uint4*)(la1 + ph * 4096) = o1;
    }
    __syncthreads();
#pragma unroll
    for (int ph = 0; ph < 4; ++ph)
      MFMA_4x4((As + ph * 4096), (Bs + ph * 4096), aoff, boff);
  }
  u16* base = P2h + (size_t)s * N8K * 128;
#pragma unroll
  for (int i = 0; i < 4; ++i)
#pragma unroll
    for (int j = 0; j < 4; ++j) {
      int c = wn + j * 16 + fm;
      int pr = m0 + wm + i * 16 + fq * 4;
#pragma unroll
      for (int ii = 0; ii < 4; ++ii)
        base[(size_t)(pr + ii) * 128 + c] = f2h(acc[i][j][ii]);
    }
}

// ---------------------------------------------------------------------------
// RED2: people1h = fp16(sum_s P2h + b2), fused BN2 sum/sumsq stats.
// Paired-column u32 fp16 loads/stores.
// ---------------------------------------------------------------------------
__global__ void k_red2(const u16* __restrict__ P2h, const float* __restrict__ bias,
                       u16* __restrict__ people1h,
                       float* __restrict__ bn2s, float* __restrict__ bn2q) {
  __shared__ float r1[512], r2[512];
  const int t = threadIdx.x;
  const int c = (t & 63) * 2, pg = t >> 6;
  const int p0 = blockIdx.x << 5;
  const float bc0 = bias[c], bc1 = bias[c + 1];
  float s1a = 0.f, s2a = 0.f, s1b = 0.f, s2b = 0.f;
  for (int pp = pg; pp < 32; pp += 4) {
    size_t o = (size_t)(p0 + pp) * 128 + c;
    float v0 = bc0, v1 = bc1;
#pragma unroll
    for (int s = 0; s < 8; ++s) {
      H2 L;
      L.u = *(const u32*)(P2h + (size_t)s * N8K * 128 + o);
      v0 += (float)L.h[0];
      v1 += (float)L.h[1];
    }
    *(u32*)(people1h + o) = pkh(v0, v1);
    s1a += v0; s2a += v0 * v0;
    s1b += v1; s2b += v1 * v1;
  }
  r1[t * 2] = s1a; r1[t * 2 + 1] = s1b;
  r2[t * 2] = s2a; r2[t * 2 + 1] = s2b;
  __syncthreads();
  if (t < 128) {
    float a = 0.f, b = 0.f;
#pragma unroll
    for (int g = 0; g < 4; ++g) {
      int idx = ((t >> 1) + 64 * g) * 2 + (t & 1);
      a += r1[idx]; b += r2[idx];
    }
    atomicAdd(&bn2s[t], a);
    atomicAdd(&bn2q[t], b);
  }
}

// ---------------------------------------------------------------------------
// BN2APPLY: out = BN2(people1h); output dtype via per-block vote on feat.
// ---------------------------------------------------------------------------
__global__ void k_bn2apply(const u16* __restrict__ people1h,
                           const float* __restrict__ bn2s, const float* __restrict__ bn2q,
                           const float* __restrict__ g2, const float* __restrict__ be2,
                           const u16* __restrict__ featprobe, void* __restrict__ outv) {
  const int flag = dvote(featprobe);
  int g = blockIdx.x * 256 + threadIdx.x;
  int p = g >> 5;
  int c = (g & 31) << 2;
  H4 L;
  L.u = *(const uint2*)(people1h + (size_t)p * 128 + c);
  f32x4 y;
#pragma unroll
  for (int jj = 0; jj < 4; ++jj) {
    int cc = c + jj;
    float mu = bn2s[cc] * (1.0f / 8192.0f);
    float var = bn2q[cc] * (1.0f / 8192.0f) - mu * mu;
    float inv = rsqrtf(var + 1e-3f);
    y[jj] = ((float)L.h[jj] - mu) * inv * g2[cc] + be2[cc];
  }
  if (flag) {
    uint2 w;
    w.x = pkf(y[0], y[1]);
    w.y = pkf(y[2], y[3]);
    *(uint2*)((u16*)outv + (size_t)p * 128 + c) = w;
  } else {
    f32x4 o = {y[0], y[1], y[2], y[3]};
    *(f32x4*)((float*)outv + (size_t)p * 128 + c) = o;
  }
}

// ---------------------------------------------------------------------------
// Workspace (~56.3 MB):
//  [0,16M)   Ph: P1h (8 x 2MB fp16) then P2h (8 x 2MB fp16)
//  [32M,36M) region1b bf16   [40M,42M) people1h fp16
//  [44M,46M) Ft bf16         [46M,48M) HT bf16
//  [48M,56M) RB2 rowbits u32 [wg=64][8192 p][4 words] (gemm1 -> gemm2)
//  [56M,..)  K1T(64K), K2T(64K), deg(32K), par, bn stats
// ---------------------------------------------------------------------------
extern "C" void kernel_launch(void* const* d_in, const int* in_sizes, int n_in,
                              void* d_out, int out_size, void* d_ws, size_t ws_size,
                              hipStream_t stream) {
  const void* feat = d_in[0];
  const int* adj   = (const int*)d_in[1];
  const void* K1   = d_in[2];
  const void* b1   = d_in[3];
  const void* g1   = d_in[4];
  const void* be1  = d_in[5];
  const void* K2   = d_in[6];
  const void* b2   = d_in[7];
  const void* g2   = d_in[8];
  const void* be2  = d_in[9];
  char* ws = (char*)d_ws;
  const size_t MB = 1u << 20;

  u16*   Ph       = (u16*)(ws);
  u16*   region1b = (u16*)(ws + 32 * MB);
  u16*   people1h = (u16*)(ws + 40 * MB);
  u16*   Ft       = (u16*)(ws + 44 * MB);
  u16*   HT       = (u16*)(ws + 46 * MB);
  u32*   RB       = (u32*)(ws + 48 * MB);
  u16*   K1T      = (u16*)(ws + 56 * MB);
  u16*   K2T      = K1T + 32768;
  float* deg      = (float*)(K2T + 32768);
  float* par      = deg + N8K;
  float* bn1s     = par + 1152;
  float* bn1q     = bn1s + 256;
  float* bn2s     = bn1q + 256;
  float* bn2q     = bn2s + 128;

  k_prep<<<289, 256, 0, stream>>>(feat, K1, K2, b1, g1, be1, b2, g2, be2,
                                  Ft, K1T, K2T, deg, par, bn1s, bn1q, bn2s, bn2q);
  k_gemm1<<<512, 256, 0, stream>>>(adj, Ft, Ph, deg, RB);
  k_projf<<<256, 256, 0, stream>>>(Ph, deg, K1T, par + 0, region1b, bn1s, bn1q);
  k_bnH<<<256, 256, 0, stream>>>(region1b, deg, bn1s, bn1q, par + 256, par + 512,
                                 K2T, HT);
  k_gemm2<<<512, 256, 0, stream>>>(RB, HT, Ph);
  k_red2<<<256, 256, 0, stream>>>(Ph, par + 768, people1h, bn2s, bn2q);
  k_bn2apply<<<1024, 256, 0, stream>>>(people1h, bn2s, bn2q, par + 896, par + 1024,
                                       (const u16*)feat, d_out);
}